// Round 10
// baseline (1417.911 us; speedup 1.0000x reference)
//
#include <hip/hip_runtime.h>
#include <hip/hip_bf16.h>
#include <math.h>

// ---------------- common helpers ----------------
typedef unsigned short u16;
typedef __attribute__((ext_vector_type(8))) short bf8v;   // 8 bf16 (4 VGPRs)
typedef __attribute__((ext_vector_type(4))) short bf4v;   // 4 bf16 (8 bytes)
typedef __attribute__((ext_vector_type(4))) float f4v;    // 4 fp32

__device__ __forceinline__ float bf2f(u16 h) {
    unsigned int u = ((unsigned int)h) << 16;
    float f;
    __builtin_memcpy(&f, &u, 4);
    return f;
}
__device__ __forceinline__ u16 f2bf(float f) {
    unsigned int u;
    __builtin_memcpy(&u, &f, 4);
    unsigned int r = (u + 0x7FFFu + ((u >> 16) & 1u)) >> 16;  // RN-even
    return (u16)r;
}
__device__ __forceinline__ float gelu_tanh(float x) {
    float x3 = x * x * x;
    float y = 0.7978845608028654f * (x + 0.044715f * x3);
    float e = __expf(2.f * y);
    float t = 1.f - 2.f / (e + 1.f);   // tanh(y), safe at +/-inf
    return 0.5f * x * (1.f + t);
}
// direct global->LDS DMA, 16B per lane (dest = wave-uniform base + lane*16)
__device__ __forceinline__ void gl_lds16(const u16* g, u16* l) {
    __builtin_amdgcn_global_load_lds(
        (const __attribute__((address_space(1))) void*)g,
        (__attribute__((address_space(3))) void*)l, 16, 0, 0);
}

#define SEQ 2048
#define DIMC 768
#define NHEAD 12
#define QKVC 2304
#define LRc 0.1f

// ---------------- fp32 -> bf16 cast ----------------
__global__ __launch_bounds__(256) void cast_f2b_kernel(
    const float* __restrict__ src, u16* __restrict__ dst, int n)
{
    int i = (blockIdx.x * 256 + threadIdx.x) * 4;
    if (i + 3 < n) {
        float4 v = *(const float4*)(src + i);
        dst[i + 0] = f2bf(v.x);
        dst[i + 1] = f2bf(v.y);
        dst[i + 2] = f2bf(v.z);
        dst[i + 3] = f2bf(v.w);
    }
}

// dual cast: z=0 -> (s0,d0), z=1 -> (s1,d1); n elements each
__global__ __launch_bounds__(256) void cast2_f2b_kernel(
    const float* __restrict__ s0, u16* __restrict__ d0,
    const float* __restrict__ s1, u16* __restrict__ d1, int n)
{
    const float* s = blockIdx.z ? s1 : s0;
    u16* d = blockIdx.z ? d1 : d0;
    int i = (blockIdx.x * 256 + threadIdx.x) * 4;
    if (i + 3 < n) {
        float4 v = *(const float4*)(s + i);
        d[i + 0] = f2bf(v.x);
        d[i + 1] = f2bf(v.y);
        d[i + 2] = f2bf(v.z);
        d[i + 3] = f2bf(v.w);
    }
}

// ---------------- fp32 -> (bf16 hi, bf16 lo) split cast ----------------
__global__ __launch_bounds__(256) void cast_split_kernel(
    const float* __restrict__ src, u16* __restrict__ hi, u16* __restrict__ lo, int n)
{
    int i = (blockIdx.x * 256 + threadIdx.x) * 4;
    if (i + 3 < n) {
        float4 v = *(const float4*)(src + i);
        float vv[4] = {v.x, v.y, v.z, v.w};
        #pragma unroll
        for (int j = 0; j < 4; ++j) {
            u16 h = f2bf(vv[j]);
            hi[i + j] = h;
            lo[i + j] = f2bf(vv[j] - bf2f(h));
        }
    }
}

// ---------------- 128x128 LDS-tiled MFMA GEMM body (register staging, R5) ----------------
// mode 0: outb=bf16(C); 1: outf=oscale*C; 2: outf+=oscale*C; 3: atomicAdd(outf, oscale*C)
__device__ __forceinline__ void gemm128_body(
    const u16* __restrict__ A, const u16* __restrict__ W,
    const float* __restrict__ bias, u16* __restrict__ outb, float* __restrict__ outf,
    int N, int Kloop, int Kstride, int act, int mode, float oscale)
{
    __shared__ u16 As[128 * 32];
    __shared__ u16 Bs[128 * 32];
    const int tid  = threadIdx.x;
    const int lane = tid & 63;
    const int wv   = tid >> 6;
    const int r16  = lane & 15;
    const int quad = lane >> 4;
    const int mh   = (wv & 1) * 64;
    const int nh   = (wv >> 1) * 64;
    const int m_blk = blockIdx.x * 128;
    const int n_blk = blockIdx.y * 128;

    const int c0 = tid, c1 = tid + 256;
    const u16* Ag0 = A + (size_t)(m_blk + (c0 >> 2)) * Kstride + (c0 & 3) * 8;
    const u16* Ag1 = A + (size_t)(m_blk + (c1 >> 2)) * Kstride + (c1 & 3) * 8;
    const u16* Wg0 = W + (size_t)(n_blk + (c0 >> 2)) * Kstride + (c0 & 3) * 8;
    const u16* Wg1 = W + (size_t)(n_blk + (c1 >> 2)) * Kstride + (c1 & 3) * 8;
    u16* As0 = As + c0 * 8;
    u16* As1 = As + c1 * 8;
    u16* Bs0 = Bs + c0 * 8;
    u16* Bs1 = Bs + c1 * 8;

    f4v acc[4][4];
    #pragma unroll
    for (int i = 0; i < 4; ++i)
        #pragma unroll
        for (int j = 0; j < 4; ++j) acc[i][j] = (f4v){0.f, 0.f, 0.f, 0.f};

    bf8v av0 = *(const bf8v*)Ag0;
    bf8v av1 = *(const bf8v*)Ag1;
    bf8v bv0 = *(const bf8v*)Wg0;
    bf8v bv1 = *(const bf8v*)Wg1;
    for (int k0 = 0; k0 < Kloop; k0 += 32) {
        __syncthreads();
        *(bf8v*)As0 = av0;
        *(bf8v*)As1 = av1;
        *(bf8v*)Bs0 = bv0;
        *(bf8v*)Bs1 = bv1;
        __syncthreads();
        if (k0 + 32 < Kloop) {
            av0 = *(const bf8v*)(Ag0 + k0 + 32);
            av1 = *(const bf8v*)(Ag1 + k0 + 32);
            bv0 = *(const bf8v*)(Wg0 + k0 + 32);
            bv1 = *(const bf8v*)(Wg1 + k0 + 32);
        }
        bf8v af[4], bfj[4];
        #pragma unroll
        for (int i = 0; i < 4; ++i)
            af[i] = *(const bf8v*)(As + (mh + i * 16 + r16) * 32 + quad * 8);
        #pragma unroll
        for (int j = 0; j < 4; ++j)
            bfj[j] = *(const bf8v*)(Bs + (nh + j * 16 + r16) * 32 + quad * 8);
        #pragma unroll
        for (int i = 0; i < 4; ++i)
            #pragma unroll
            for (int j = 0; j < 4; ++j)
                acc[i][j] = __builtin_amdgcn_mfma_f32_16x16x32_bf16(af[i], bfj[j], acc[i][j], 0, 0, 0);
    }

    #pragma unroll
    for (int j = 0; j < 4; ++j) {
        int gn = n_blk + nh + j * 16 + r16;
        float bvv = bias ? bias[gn] : 0.f;
        #pragma unroll
        for (int i = 0; i < 4; ++i) {
            #pragma unroll
            for (int rr = 0; rr < 4; ++rr) {
                int gm = m_blk + mh + i * 16 + quad * 4 + rr;
                float v = acc[i][j][rr] + bvv;
                if (act == 1) v = gelu_tanh(v);
                else if (act == 2) v = 1.f / (1.f + __expf(-v));
                size_t oi = (size_t)gm * N + gn;
                if (mode == 0) outb[oi] = f2bf(v);
                else if (mode == 1) outf[oi] = oscale * v;
                else if (mode == 2) outf[oi] += oscale * v;
                else atomicAdd(outf + oi, oscale * v);
            }
        }
    }
}

// ---------------- m97-style DMA body: single-buffer LDS, global_load_lds, ----------------
// 2 barriers per K-step. Per-block DMA drain is exposed; hidden by >=2-3
// co-resident blocks/CU -- use ONLY for grids >= ~576 blocks.
__device__ __forceinline__ void gemm128_dma_body(
    const u16* __restrict__ A, const u16* __restrict__ W,
    const float* __restrict__ bias, u16* __restrict__ outb, float* __restrict__ outf,
    int N, int Kloop, int Kstride, int act, int mode, float oscale)
{
    __shared__ u16 As[128 * 32];
    __shared__ u16 Bs[128 * 32];
    const int tid  = threadIdx.x;
    const int lane = tid & 63;
    const int wv   = tid >> 6;
    const int r16  = lane & 15;
    const int quad = lane >> 4;
    const int mh   = (wv & 1) * 64;
    const int nh   = (wv >> 1) * 64;
    const int m_blk = blockIdx.x * 128;
    const int n_blk = blockIdx.y * 128;

    const int c0 = tid, c1 = tid + 256;
    const u16* Ag0 = A + (size_t)(m_blk + (c0 >> 2)) * Kstride + (c0 & 3) * 8;
    const u16* Ag1 = A + (size_t)(m_blk + (c1 >> 2)) * Kstride + (c1 & 3) * 8;
    const u16* Wg0 = W + (size_t)(n_blk + (c0 >> 2)) * Kstride + (c0 & 3) * 8;
    const u16* Wg1 = W + (size_t)(n_blk + (c1 >> 2)) * Kstride + (c1 & 3) * 8;
    u16* As0 = As + c0 * 8;
    u16* As1 = As + c1 * 8;
    u16* Bs0 = Bs + c0 * 8;
    u16* Bs1 = Bs + c1 * 8;

    f4v acc[4][4];
    #pragma unroll
    for (int i = 0; i < 4; ++i)
        #pragma unroll
        for (int j = 0; j < 4; ++j) acc[i][j] = (f4v){0.f, 0.f, 0.f, 0.f};

    for (int k0 = 0; k0 < Kloop; k0 += 32) {
        __syncthreads();               // previous compute done reading LDS
        gl_lds16(Ag0 + k0, As0);
        gl_lds16(Ag1 + k0, As1);
        gl_lds16(Wg0 + k0, Bs0);
        gl_lds16(Wg1 + k0, Bs1);
        __syncthreads();               // vmcnt(0) drain -> tile ready
        bf8v af[4], bfj[4];
        #pragma unroll
        for (int i = 0; i < 4; ++i)
            af[i] = *(const bf8v*)(As + (mh + i * 16 + r16) * 32 + quad * 8);
        #pragma unroll
        for (int j = 0; j < 4; ++j)
            bfj[j] = *(const bf8v*)(Bs + (nh + j * 16 + r16) * 32 + quad * 8);
        #pragma unroll
        for (int i = 0; i < 4; ++i)
            #pragma unroll
            for (int j = 0; j < 4; ++j)
                acc[i][j] = __builtin_amdgcn_mfma_f32_16x16x32_bf16(af[i], bfj[j], acc[i][j], 0, 0, 0);
    }

    #pragma unroll
    for (int j = 0; j < 4; ++j) {
        int gn = n_blk + nh + j * 16 + r16;
        float bvv = bias ? bias[gn] : 0.f;
        #pragma unroll
        for (int i = 0; i < 4; ++i) {
            #pragma unroll
            for (int rr = 0; rr < 4; ++rr) {
                int gm = m_blk + mh + i * 16 + quad * 4 + rr;
                float v = acc[i][j][rr] + bvv;
                if (act == 1) v = gelu_tanh(v);
                else if (act == 2) v = 1.f / (1.f + __expf(-v));
                size_t oi = (size_t)gm * N + gn;
                if (mode == 0) outb[oi] = f2bf(v);
                else if (mode == 1) outf[oi] = oscale * v;
                else if (mode == 2) outf[oi] += oscale * v;
                else atomicAdd(outf + oi, oscale * v);
            }
        }
    }
}

__global__ __launch_bounds__(256) void gemm128_kernel(
    const u16* __restrict__ A, const u16* __restrict__ W,
    const float* __restrict__ bias, u16* __restrict__ outb, float* __restrict__ outf,
    int N, int K, int act, int mode, float oscale)
{
    gemm128_body(A, W, bias, outb, outf, N, K, K, act, mode, oscale);
}

// DMA variant (big grids only)
__global__ __launch_bounds__(256) void gemm128_dma_kernel(
    const u16* __restrict__ A, const u16* __restrict__ W,
    const float* __restrict__ bias, u16* __restrict__ outb, float* __restrict__ outf,
    int N, int K, int act, int mode, float oscale)
{
    gemm128_dma_body(A, W, bias, outb, outf, N, K, K, act, mode, oscale);
}

// dual: z=0 -> set0, z=1 -> set1 (both mode 0, act 0, same N/K)
__global__ __launch_bounds__(256) void gemm128_dual_kernel(
    const u16* __restrict__ A0, const u16* __restrict__ W0,
    const float* __restrict__ b0, u16* __restrict__ o0,
    const u16* __restrict__ A1, const u16* __restrict__ W1,
    const float* __restrict__ b1, u16* __restrict__ o1,
    int N, int K)
{
    if (blockIdx.z == 0) gemm128_body(A0, W0, b0, o0, nullptr, N, K, K, 0, 0, 0.f);
    else                 gemm128_body(A1, W1, b1, o1, nullptr, N, K, K, 0, 0, 0.f);
}

// K-split accumulating gemm (DMA staging): z = K-chunk; atomicAdd into pre-zeroed outf.
__global__ __launch_bounds__(256) void gemm128_ksplit_kernel(
    const u16* __restrict__ A, const u16* __restrict__ W,
    const float* __restrict__ bias, float* __restrict__ outf,
    int N, int Kstride, int KC, float oscale)
{
    const int z = blockIdx.z;
    gemm128_dma_body(A + (size_t)z * KC, W + (size_t)z * KC, z == 0 ? bias : nullptr,
                     nullptr, outf, N, KC, Kstride, 0, 3, oscale);
}

// ---------------- split-precision MFMA GEMM (~fp32 quality), 64x64, dual-z ----------------
__global__ __launch_bounds__(256) void gemm_split_kernel(
    const u16* __restrict__ Ahi, const u16* __restrict__ Alo,
    const u16* __restrict__ W0hi, const u16* __restrict__ W0lo, float* __restrict__ out0,
    const u16* __restrict__ W1hi, const u16* __restrict__ W1lo, float* __restrict__ out1,
    int M, int N, int K)
{
    const u16* Whi = blockIdx.z ? W1hi : W0hi;
    const u16* Wlo = blockIdx.z ? W1lo : W0lo;
    float* outf    = blockIdx.z ? out1 : out0;

    const int lane = threadIdx.x & 63;
    const int wv   = threadIdx.x >> 6;
    const int m0   = blockIdx.x * 64 + wv * 16;
    const int n0   = blockIdx.y * 64;
    const int r16  = lane & 15;
    const int quad = lane >> 4;

    const size_t arow = (size_t)(m0 + r16) * K + quad * 8;
    const size_t wrow = (size_t)(n0 + r16) * K + quad * 8;
    const size_t wstride = (size_t)16 * K;

    f4v acc[4];
    #pragma unroll
    for (int j = 0; j < 4; ++j) acc[j] = (f4v){0.f, 0.f, 0.f, 0.f};

    for (int k0 = 0; k0 < K; k0 += 32) {
        bf8v ah = *(const bf8v*)(Ahi + arow + k0);
        bf8v al = *(const bf8v*)(Alo + arow + k0);
        #pragma unroll
        for (int j = 0; j < 4; ++j) {
            bf8v bh = *(const bf8v*)(Whi + wrow + j * wstride + k0);
            bf8v bl = *(const bf8v*)(Wlo + wrow + j * wstride + k0);
            acc[j] = __builtin_amdgcn_mfma_f32_16x16x32_bf16(ah, bh, acc[j], 0, 0, 0);
            acc[j] = __builtin_amdgcn_mfma_f32_16x16x32_bf16(ah, bl, acc[j], 0, 0, 0);
            acc[j] = __builtin_amdgcn_mfma_f32_16x16x32_bf16(al, bh, acc[j], 0, 0, 0);
        }
    }

    #pragma unroll
    for (int j = 0; j < 4; ++j) {
        int gn = n0 + j * 16 + r16;
        #pragma unroll
        for (int rr = 0; rr < 4; ++rr) {
            int gm = m0 + quad * 4 + rr;
            outf[(size_t)gm * N + gn] = acc[j][rr];
        }
    }
}

// ---------------- sliding-window attention (MFMA) ----------------
#define NJ 527
#define NJP 548
__global__ __launch_bounds__(256) void attn_kernel(
    const u16* __restrict__ qkv, u16* __restrict__ outp)
{
    const int bh = blockIdx.y;
    const int b = bh / NHEAD, h = bh % NHEAD;
    const int q0 = blockIdx.x * 16;
    const int jbase = q0 - 511;
    const int tid = threadIdx.x;
    const int lane = tid & 63;
    const int wv = tid >> 6;
    const int r16 = lane & 15;
    const int quad = lane >> 4;

    __shared__ float ss[16][NJP];
    __shared__ float redbuf[16][17];
    __shared__ float rowmax[16];
    __shared__ float rowinv[16];

    const size_t qrow = (size_t)(b * SEQ + q0 + r16) * QKVC + h * 64 + quad * 8;
    bf8v qf0 = *(const bf8v*)(qkv + qrow);
    bf8v qf1 = *(const bf8v*)(qkv + qrow + 32);

    for (int jt = wv; jt < 33; jt += 4) {
        int js_l = jt * 16 + r16;
        int j = jbase + js_l;
        int jc = j & (SEQ - 1);
        const u16* kp = qkv + (size_t)(b * SEQ + jc) * QKVC + DIMC + h * 64 + quad * 8;
        bf8v kf0 = *(const bf8v*)kp;
        bf8v kf1 = *(const bf8v*)(kp + 32);
        f4v acc = (f4v){0.f, 0.f, 0.f, 0.f};
        acc = __builtin_amdgcn_mfma_f32_16x16x32_bf16(qf0, kf0, acc, 0, 0, 0);
        acc = __builtin_amdgcn_mfma_f32_16x16x32_bf16(qf1, kf1, acc, 0, 0, 0);
        if (js_l < NJ) {
            #pragma unroll
            for (int rr = 0; rr < 4; ++rr) {
                int row = quad * 4 + rr;
                bool ok = (j >= 0) && (js_l >= row) && (js_l <= row + 511);
                ss[row][js_l] = ok ? 0.125f * acc[rr] : -1e30f;
            }
        }
    }
    for (int t = tid; t < 16 * 17; t += 256)
        ss[t / 17][527 + t % 17] = 0.f;
    __syncthreads();

    {
        int r = tid >> 4, l16 = tid & 15;
        float mx = -1e30f;
        #pragma unroll 1
        for (int js = l16; js < NJ; js += 16) mx = fmaxf(mx, ss[r][js]);
        redbuf[r][l16] = mx;
        __syncthreads();
        if (l16 == 0) {
            float m = -1e30f;
            #pragma unroll
            for (int i = 0; i < 16; ++i) m = fmaxf(m, redbuf[r][i]);
            rowmax[r] = m;
        }
        __syncthreads();
        float rm = rowmax[r];
        float sm = 0.f;
        #pragma unroll 1
        for (int js = l16; js < NJ; js += 16) {
            float p = __expf(ss[r][js] - rm);
            ss[r][js] = p;
            sm += p;
        }
        redbuf[r][l16] = sm;
        __syncthreads();
        if (l16 == 0) {
            float s = 0.f;
            #pragma unroll
            for (int i = 0; i < 16; ++i) s += redbuf[r][i];
            rowinv[r] = 1.f / s;
        }
        __syncthreads();
    }

    {
        const int d0 = wv * 16;
        const u16* vp = qkv + (size_t)b * SEQ * QKVC + 2 * DIMC + h * 64 + d0 + r16;
        f4v oacc = (f4v){0.f, 0.f, 0.f, 0.f};
        for (int k0 = 0; k0 < 544; k0 += 32) {
            float4 p0 = *(const float4*)&ss[r16][k0 + quad * 8];
            float4 p1 = *(const float4*)&ss[r16][k0 + quad * 8 + 4];
            bf8v pa;
            pa[0] = (short)f2bf(p0.x); pa[1] = (short)f2bf(p0.y);
            pa[2] = (short)f2bf(p0.z); pa[3] = (short)f2bf(p0.w);
            pa[4] = (short)f2bf(p1.x); pa[5] = (short)f2bf(p1.y);
            pa[6] = (short)f2bf(p1.z); pa[7] = (short)f2bf(p1.w);
            bf8v vb;
            #pragma unroll
            for (int m = 0; m < 8; ++m) {
                int j = jbase + k0 + quad * 8 + m;
                int jc = j & (SEQ - 1);
                vb[m] = (short)vp[(size_t)jc * QKVC];
            }
            oacc = __builtin_amdgcn_mfma_f32_16x16x32_bf16(pa, vb, oacc, 0, 0, 0);
        }
        #pragma unroll
        for (int rr = 0; rr < 4; ++rr) {
            int row = quad * 4 + rr;
            size_t oi = (size_t)(b * SEQ + q0 + row) * DIMC + h * 64 + d0 + r16;
            outp[oi] = f2bf(oacc[rr] * rowinv[row]);
        }
    }
}

// ---------------- residual + LayerNorm ----------------
__global__ __launch_bounds__(256) void ln_res_kernel(
    const void* __restrict__ xv, int xf32, const void* __restrict__ yv, int yf32,
    const float* __restrict__ g, const float* __restrict__ be,
    u16* __restrict__ outb, float* __restrict__ outf, int ldout)
{
    const int row = blockIdx.x;
    const int t = threadIdx.x;
    const size_t base = (size_t)row * DIMC;
    float vv[3];
    float s = 0.f, s2 = 0.f;
    #pragma unroll
    for (int i = 0; i < 3; ++i) {
        int d = t + i * 256;
        float a = xf32 ? ((const float*)xv)[base + d] : bf2f(((const u16*)xv)[base + d]);
        float y = yf32 ? ((const float*)yv)[base + d] : bf2f(((const u16*)yv)[base + d]);
        float w = a + y;
        vv[i] = w;
        s += w;
        s2 += w * w;
    }
    #pragma unroll
    for (int o = 32; o > 0; o >>= 1) {
        s  += __shfl_down(s, o);
        s2 += __shfl_down(s2, o);
    }
    __shared__ float rs[4], rq[4], mb[2];
    if ((t & 63) == 0) { rs[t >> 6] = s; rq[t >> 6] = s2; }
    __syncthreads();
    if (t == 0) {
        float S1 = rs[0] + rs[1] + rs[2] + rs[3];
        float S2 = rq[0] + rq[1] + rq[2] + rq[3];
        float mean = S1 * (1.f / 768.f);
        float var = S2 * (1.f / 768.f) - mean * mean;
        mb[0] = mean;
        mb[1] = rsqrtf(var + 1e-5f);
    }
    __syncthreads();
    float mean = mb[0], rstd = mb[1];
    #pragma unroll
    for (int i = 0; i < 3; ++i) {
        int d = t + i * 256;
        float v = (vv[i] - mean) * rstd * g[d] + be[d];
        if (outb) outb[(size_t)row * ldout + d] = f2bf(v);
        else      outf[(size_t)row * ldout + d] = v;
    }
}

// merged LN for x_local / x_global
__global__ __launch_bounds__(256) void ln_res2_kernel(
    const float* __restrict__ x,
    const u16* __restrict__ y0, const float* __restrict__ g0, const float* __restrict__ b0,
    u16* __restrict__ o0,
    const u16* __restrict__ y1, const float* __restrict__ g1, const float* __restrict__ b1,
    u16* __restrict__ o1, int M)
{
    int row = blockIdx.x;
    const u16* y; const float* g; const float* be; u16* ob;
    if (row < M) { y = y0; g = g0; be = b0; ob = o0; }
    else { row -= M; y = y1; g = g1; be = b1; ob = o1; }
    const int t = threadIdx.x;
    const size_t base = (size_t)row * DIMC;
    float vv[3];
    float s = 0.f, s2 = 0.f;
    #pragma unroll
    for (int i = 0; i < 3; ++i) {
        int d = t + i * 256;
        float w = x[base + d] + bf2f(y[base + d]);
        vv[i] = w;
        s += w;
        s2 += w * w;
    }
    #pragma unroll
    for (int o = 32; o > 0; o >>= 1) {
        s  += __shfl_down(s, o);
        s2 += __shfl_down(s2, o);
    }
    __shared__ float rs[4], rq[4], mb[2];
    if ((t & 63) == 0) { rs[t >> 6] = s; rq[t >> 6] = s2; }
    __syncthreads();
    if (t == 0) {
        float S1 = rs[0] + rs[1] + rs[2] + rs[3];
        float S2 = rq[0] + rq[1] + rq[2] + rq[3];
        float mean = S1 * (1.f / 768.f);
        float var = S2 * (1.f / 768.f) - mean * mean;
        mb[0] = mean;
        mb[1] = rsqrtf(var + 1e-5f);
    }
    __syncthreads();
    float mean = mb[0], rstd = mb[1];
    #pragma unroll
    for (int i = 0; i < 3; ++i) {
        int d = t + i * 256;
        float v = (vv[i] - mean) * rstd * g[d] + be[d];
        ob[(size_t)row * 1536 + d] = f2bf(v);
    }
}

// ---------------- chunked delta-rule scan (R7-proven) ----------------
__global__ __launch_bounds__(64) void scanA_kernel(
    const u16* __restrict__ tq, const float* __restrict__ tk,
    float* __restrict__ Tm, float* __restrict__ Sm)
{
    const int bid = blockIdx.x;          // 24*32
    const int bh = bid >> 5, c = bid & 31;
    const int b = bh / NHEAD, h = bh % NHEAD;
    const int lane = threadIdx.x;

    __shared__ float Ks[64][68];
    __shared__ float As[64][68];     // A, later reused for S
    __shared__ float Ts[64][68];
    __shared__ u16   Qs[64][72];

    const size_t rowb = (size_t)b * SEQ * DIMC + h * 64;
    const int rg = lane >> 4, c4 = (lane & 15) * 4;
    #pragma unroll 4
    for (int i = 0; i < 16; ++i) {
        int row = i * 4 + rg;
        size_t g = rowb + (size_t)(c * 64 + row) * DIMC + c4;
        *(float4*)&Ks[row][c4] = *(const float4*)(tk + g);
        *(bf4v*)&Qs[row][c4]   = *(const bf4v*)(tq + g);
    }
    __syncthreads();

    float4 kr4[16];
    #pragma unroll
    for (int d4 = 0; d4 < 16; ++d4) kr4[d4] = *(float4*)&Ks[lane][d4 * 4];

    for (int t = 0; t < 64; ++t) {
        float a = 0.f;
        #pragma unroll
        for (int d4 = 0; d4 < 16; ++d4) {
            float4 kt = *(float4*)&Ks[t][d4 * 4];
            a += kt.x * kr4[d4].x + kt.y * kr4[d4].y + kt.z * kr4[d4].z + kt.w * kr4[d4].w;
        }
        As[t][lane] = (lane < t) ? LRc * a : 0.f;
    }
    Ts[0][lane] = (lane == 0) ? 1.f : 0.f;
    for (int t = 1; t < 64; ++t) {
        float s = (lane == t) ? 1.f : 0.f;
        for (int tau = 0; tau < t; ++tau)
            s -= As[t][tau] * Ts[tau][lane];
        Ts[t][lane] = s;
    }
    for (int t = 0; t < 64; ++t) {
        float a = 0.f;
        #pragma unroll
        for (int d4 = 0; d4 < 16; ++d4) {
            bf4v qt = *(bf4v*)&Qs[t][d4 * 4];
            a += bf2f((u16)qt[0]) * kr4[d4].x + bf2f((u16)qt[1]) * kr4[d4].y
               + bf2f((u16)qt[2]) * kr4[d4].z + bf2f((u16)qt[3]) * kr4[d4].w;
        }
        As[t][lane] = (lane <= t) ? a : 0.f;
    }
    __syncthreads();
    float* Tg = Tm + (size_t)bid * 4096;
    float* Sg = Sm + (size_t)bid * 4096;
    #pragma unroll 4
    for (int i = 0; i < 16; ++i) {
        int row = i * 4 + rg;
        *(float4*)(Tg + row * 64 + c4) = *(float4*)&Ts[row][c4];
        *(float4*)(Sg + row * 64 + c4) = *(float4*)&As[row][c4];
    }
}

__global__ __launch_bounds__(256) void scanB_kernel(
    const u16* __restrict__ tq, const float* __restrict__ tk, const float* __restrict__ tv,
    const float* __restrict__ Tm, const float* __restrict__ Sm,
    u16* __restrict__ tito, float* __restrict__ mout)
{
    const int bid = blockIdx.x;          // 96
    const int bh = bid >> 2, eh = bid & 3;
    const int b = bh / NHEAD, h = bh % NHEAD;
    const int tid = threadIdx.x;
    const int tx = tid & 3;
    const int r  = tid >> 2;
    const int cc4 = tx * 4;
    const int e0 = eh * 16;

    __shared__ float Ms[64][20];
    __shared__ float Ys[64][20];
    __shared__ float Us[64][20];
    __shared__ float XK[64][68];
    __shared__ float XT[64][68];
    __shared__ float XS[64][68];
    __shared__ u16   Qt[64][72];

    const size_t rowb = (size_t)b * SEQ * DIMC + h * 64;

    for (int i = tid; i < 64 * 20; i += 256) (&Ms[0][0])[i] = 0.f;

    const int srow = tid & 63;
    const int scc  = (tid >> 6) * 16;

    for (int ch = 0; ch < 32; ++ch) {
        const size_t crow = rowb + (size_t)ch * 64 * DIMC;
        {
            const float* s = tk + crow + (size_t)srow * DIMC + scc;
            float4 a0 = *(const float4*)(s + 0), a1 = *(const float4*)(s + 4),
                   a2 = *(const float4*)(s + 8), a3 = *(const float4*)(s + 12);
            float av[16] = {a0.x, a0.y, a0.z, a0.w, a1.x, a1.y, a1.z, a1.w,
                            a2.x, a2.y, a2.z, a2.w, a3.x, a3.y, a3.z, a3.w};
            #pragma unroll
            for (int j = 0; j < 16; ++j) XK[scc + j][srow] = av[j];
            const u16* qg = tq + crow + (size_t)srow * DIMC + scc;
            bf8v q0 = *(const bf8v*)(qg), q1 = *(const bf8v*)(qg + 8);
            #pragma unroll
            for (int j = 0; j < 8; ++j) {
                Qt[scc + j][srow]     = (u16)q0[j];
                Qt[scc + 8 + j][srow] = (u16)q1[j];
            }
        }
        __syncthreads();                 // sync 1

        const float* tsrc = Tm + ((size_t)(bh * 32 + ch)) * 4096 + (size_t)srow * 64 + scc;
        float4 t0 = *(const float4*)(tsrc + 0), t1 = *(const float4*)(tsrc + 4),
               t2 = *(const float4*)(tsrc + 8), t3 = *(const float4*)(tsrc + 12);
        float4 v0 = *(const float4*)(tv + crow + (size_t)r * DIMC + e0 + cc4);

        float p[4] = {0.f, 0.f, 0.f, 0.f};
        float oa[4] = {0.f, 0.f, 0.f, 0.f};
        #pragma unroll 4
        for (int k = 0; k < 64; ++k) {
            float a = XK[k][r];
            float q = bf2f(Qt[k][r]);
            float4 m = *(float4*)&Ms[k][cc4];
            p[0] += a * m.x; p[1] += a * m.y; p[2] += a * m.z; p[3] += a * m.w;
            oa[0] += q * m.x; oa[1] += q * m.y; oa[2] += q * m.z; oa[3] += q * m.w;
        }
        {
            float av[16] = {t0.x, t0.y, t0.z, t0.w, t1.x, t1.y, t1.z, t1.w,
                            t2.x, t2.y, t2.z, t2.w, t3.x, t3.y, t3.z, t3.w};
            #pragma unroll
            for (int j = 0; j < 16; ++j) XT[scc + j][srow] = av[j];
            Ys[r][cc4 + 0] = LRc * (v0.x - p[0]);
            Ys[r][cc4 + 1] = LRc * (v0.y - p[1]);
            Ys[r][cc4 + 2] = LRc * (v0.z - p[2]);
            Ys[r][cc4 + 3] = LRc * (v0.w - p[3]);
        }
        __syncthreads();                 // sync 2

        const float* ssrc = Sm + ((size_t)(bh * 32 + ch)) * 4096 + (size_t)srow * 64 + scc;
        float4 s0 = *(const float4*)(ssrc + 0), s1 = *(const float4*)(ssrc + 4),
               s2 = *(const float4*)(ssrc + 8), s3 = *(const float4*)(ssrc + 12);

        float u[4] = {0.f, 0.f, 0.f, 0.f};
        #pragma unroll 4
        for (int k = 0; k < 64; ++k) {
            float a = XT[k][r];
            float4 bb = *(float4*)&Ys[k][cc4];
            u[0] += a * bb.x; u[1] += a * bb.y; u[2] += a * bb.z; u[3] += a * bb.w;
        }
        {
            float av[16] = {s0.x, s0.y, s0.z, s0.w, s1.x, s1.y, s1.z, s1.w,
                            s2.x, s2.y, s2.z, s2.w, s3.x, s3.y, s3.z, s3.w};
            #pragma unroll
            for (int j = 0; j < 16; ++j) XS[scc + j][srow] = av[j];
            #pragma unroll
            for (int j = 0; j < 4; ++j) Us[r][cc4 + j] = u[j];
        }
        __syncthreads();                 // sync 3

        float m0[4];
        #pragma unroll
        for (int j = 0; j < 4; ++j) m0[j] = Ms[r][cc4 + j];
        #pragma unroll 4
        for (int k = 0; k < 64; ++k) {
            float sa = XS[k][r];
            float ka = XK[r][k];
            float4 uu = *(float4*)&Us[k][cc4];
            oa[0] += sa * uu.x; oa[1] += sa * uu.y; oa[2] += sa * uu.z; oa[3] += sa * uu.w;
            m0[0] += ka * uu.x; m0[1] += ka * uu.y; m0[2] += ka * uu.z; m0[3] += ka * uu.w;
        }
        #pragma unroll
        for (int j = 0; j < 4; ++j) Ms[r][cc4 + j] = m0[j];
        {
            u16* op = tito + crow + (size_t)r * DIMC + e0 + cc4;
            bf4v w;
            #pragma unroll
            for (int j = 0; j < 4; ++j) w[j] = (short)f2bf(oa[j]);
            *(bf4v*)op = w;
        }
        __syncthreads();                 // sync 4
    }
    {
        float* mg = mout + (size_t)bh * 4096 + (size_t)r * 64 + e0 + cc4;
        *(float4*)mg = *(float4*)&Ms[r][cc4];
    }
}

// ---------------- gated combine ----------------
__global__ __launch_bounds__(768) void combine_kernel(
    const u16* __restrict__ xlg, const u16* __restrict__ gate, u16* __restrict__ xc)
{
    const int row = blockIdx.x;
    const int t = threadIdx.x;
    float g = bf2f(gate[(size_t)row * DIMC + t]);
    float xl = bf2f(xlg[(size_t)row * 1536 + t]);
    float xg = bf2f(xlg[(size_t)row * 1536 + 768 + t]);
    xc[(size_t)row * DIMC + t] = f2bf(g * xl + (1.f - g) * xg);
}

// ---------------- launcher ----------------
extern "C" void kernel_launch(void* const* d_in, const int* in_sizes, int n_in,
                              void* d_out, int out_size, void* d_ws, size_t ws_size,
                              hipStream_t stream) {
    const float* x          = (const float*)d_in[0];
    const float* in_proj_w  = (const float*)d_in[1];
    const float* in_proj_b  = (const float*)d_in[2];
    const float* out_proj_w = (const float*)d_in[3];
    const float* out_proj_b = (const float*)d_in[4];
    const float* ln_local_g = (const float*)d_in[5];
    const float* ln_local_b = (const float*)d_in[6];
    const float* t_wq       = (const float*)d_in[7];
    const float* t_wk       = (const float*)d_in[8];
    const float* t_wv       = (const float*)d_in[9];
    const float* t_wo       = (const float*)d_in[10];
    const float* ln_tit_g   = (const float*)d_in[11];
    const float* ln_tit_b   = (const float*)d_in[12];
    const float* gate_w     = (const float*)d_in[13];
    const float* gate_b     = (const float*)d_in[14];
    const float* cms_w1     = (const float*)d_in[15];
    const float* cms_b1     = (const float*)d_in[16];
    const float* cms_w2     = (const float*)d_in[17];
    const float* cms_b2     = (const float*)d_in[18];
    const float* ln_cms_g   = (const float*)d_in[19];
    const float* ln_cms_b   = (const float*)d_in[20];

    const int Mrows = 2 * SEQ;  // 4096

    // ---- workspace (u16 offsets), cap 37,748,736 u16 = 75,497,472 B ----
    u16* ws = (u16*)d_ws;
    u16*   qkv   = ws + 0;
    u16*   lout  = ws + 0;
    u16*   gout  = ws + 3145728;
    u16*   gact  = ws + 6291456;
    u16*   tq16  = ws + 9437184;
    u16*   wB    = ws + 9437184;      // 768x768 bf16 (589824)
    u16*   wB2   = ws + 10027008;     // second weight slot (t_wo)
    u16*   w_inp = ws + 12582912;
    float* tkf   = (float*)(ws + 12582912);
    u16*   W1S   = ws + 12582912;
    u16*   W2S   = ws + 14942208;
    float* tvf   = (float*)(ws + 18874368);
    u16*   w_tqb = ws + 25165824;
    u16*   tito  = ws + 25165824;
    u16*   w_hi  = ws + 28311552;
    u16*   w_lo  = ws + 28901376;
    u16*   w_hi2 = ws + 29491200;
    u16*   w_lo2 = ws + 30081024;
    u16*   attn_o= ws + 28311552;
    u16*   xc    = ws + 28311552;
    u16*   x_hi  = ws + 31457280;
    u16*   x_lo  = ws + 34603008;
    u16*   xlg   = ws + 31457280;
    u16*   h     = ws + 0;            // CMS h: A+B regions dead after combine

    float* out32 = (float*)d_out;
    float* cmsacc = out32;
    float* mout  = out32 + (size_t)Mrows * DIMC;

    float* Tmat = (float*)(ws + 31457280);   // G region (exact fit)
    float* Smat = out32;                     // cmsacc region as scratch pre-CMS

    auto cast = [&](const float* src, u16* dst, int n) {
        cast_f2b_kernel<<<(n + 1023) / 1024, 256, 0, stream>>>(src, dst, n);
    };
    auto gemm = [&](const u16* A, const u16* W, const float* bias, u16* ob, float* of,
                    int M, int N, int K, int act, int mode, float oscale) {
        gemm128_kernel<<<dim3(M / 128, N / 128), 256, 0, stream>>>(
            A, W, bias, ob, of, N, K, act, mode, oscale);
    };
    auto gemm_dma = [&](const u16* A, const u16* W, const float* bias, u16* ob, float* of,
                        int M, int N, int K, int act, int mode, float oscale) {
        gemm128_dma_kernel<<<dim3(M / 128, N / 128), 256, 0, stream>>>(
            A, W, bias, ob, of, N, K, act, mode, oscale);
    };
    auto split = [&](const float* src, u16* hi, u16* lo, int n) {
        cast_split_kernel<<<(n + 1023) / 1024, 256, 0, stream>>>(src, hi, lo, n);
    };

    // 1. split-cast x
    split(x, x_hi, x_lo, Mrows * DIMC);
    // 2. qkv projection (DMA body: grid 576 blocks)
    cast(in_proj_w, w_inp, QKVC * DIMC);
    gemm_dma(x_hi, w_inp, in_proj_b, qkv, nullptr, Mrows, QKVC, DIMC, 0, 0, 0.f);
    // 3+4. tk & tv split-precision in ONE dual launch
    split(t_wk, w_hi, w_lo, DIMC * DIMC);
    split(t_wv, w_hi2, w_lo2, DIMC * DIMC);
    gemm_split_kernel<<<dim3(Mrows / 64, DIMC / 64, 2), 256, 0, stream>>>(
        x_hi, x_lo, w_hi, w_lo, tkf, w_hi2, w_lo2, tvf, Mrows, DIMC, DIMC);
    // 5. tq (bf16)
    cast(t_wq, w_tqb, DIMC * DIMC);
    gemm(x_hi, w_tqb, nullptr, tq16, nullptr, Mrows, DIMC, DIMC, 0, 0, 0.f);
    // 6. sliding-window attention
    attn_kernel<<<dim3(SEQ / 16, 2 * NHEAD), 256, 0, stream>>>(qkv, attn_o);
    // 7. chunked delta-rule scan
    scanA_kernel<<<24 * 32, 64, 0, stream>>>(tq16, tkf, Tmat, Smat);
    scanB_kernel<<<24 * 4, 256, 0, stream>>>(tq16, tkf, tvf, Tmat, Smat, tito, mout);
    // 8+10. out_proj + titans out_proj in ONE dual launch
    cast2_f2b_kernel<<<dim3((DIMC * DIMC + 1023) / 1024, 1, 2), 256, 0, stream>>>(
        out_proj_w, wB, t_wo, wB2, DIMC * DIMC);
    gemm128_dual_kernel<<<dim3(Mrows / 128, DIMC / 128, 2), 256, 0, stream>>>(
        attn_o, wB, out_proj_b, lout, tito, wB2, nullptr, gout, DIMC, DIMC);
    // 9+11. x_local & x_global LayerNorms in ONE launch
    ln_res2_kernel<<<2 * Mrows, 256, 0, stream>>>(
        x, lout, ln_local_g, ln_local_b, xlg,
        gout, ln_tit_g, ln_tit_b, xlg + 768, Mrows);
    // 12. gate
    cast(gate_w, wB, DIMC * 2 * DIMC);
    gemm(xlg, wB, gate_b, gact, nullptr, Mrows, DIMC, 2 * DIMC, 2, 0, 0.f);
    // 13. combine -> xc
    combine_kernel<<<Mrows, 768, 0, stream>>>(xlg, gact, xc);
    // 14. CMS merged over full M. gemm1: DMA body (768 blocks). gemm2: DMA
    //     K-split x4 (768 blocks) with atomicAdd into pre-zeroed cmsacc.
    hipMemsetAsync(cmsacc, 0, (size_t)Mrows * DIMC * sizeof(float), stream);
    for (int l = 0; l < 4; ++l) {
        cast2_f2b_kernel<<<dim3((2359296 + 1023) / 1024, 1, 2), 256, 0, stream>>>(
            cms_w1 + (size_t)l * 2359296, W1S, cms_w2 + (size_t)l * 2359296, W2S, 2359296);
        gemm_dma(xc, W1S, cms_b1 + l * 3072, h, nullptr, Mrows, 3072, DIMC, 1, 0, 0.f);
        gemm128_ksplit_kernel<<<dim3(Mrows / 128, DIMC / 128, 4), 256, 0, stream>>>(
            h, W2S, cms_b2 + l * DIMC, cmsacc, DIMC, 3072, 768, 0.25f);
    }
    // 15. final LN -> d_out
    ln_res_kernel<<<Mrows, 256, 0, stream>>>(xc, 0, cmsacc, 1, ln_cms_g, ln_cms_b, nullptr, out32, DIMC);

    (void)in_sizes; (void)n_in; (void)out_size; (void)ws_size;
}

// Round 11
// 1289.123 us; speedup vs baseline: 1.0999x; 1.0999x over previous
//
#include <hip/hip_runtime.h>
#include <hip/hip_bf16.h>
#include <math.h>

// ---------------- common helpers ----------------
typedef unsigned short u16;
typedef __attribute__((ext_vector_type(8))) short bf8v;   // 8 bf16 (4 VGPRs)
typedef __attribute__((ext_vector_type(4))) short bf4v;   // 4 bf16 (8 bytes)
typedef __attribute__((ext_vector_type(4))) float f4v;    // 4 fp32

__device__ __forceinline__ float bf2f(u16 h) {
    unsigned int u = ((unsigned int)h) << 16;
    float f;
    __builtin_memcpy(&f, &u, 4);
    return f;
}
__device__ __forceinline__ u16 f2bf(float f) {
    unsigned int u;
    __builtin_memcpy(&u, &f, 4);
    unsigned int r = (u + 0x7FFFu + ((u >> 16) & 1u)) >> 16;  // RN-even
    return (u16)r;
}
__device__ __forceinline__ float gelu_tanh(float x) {
    float x3 = x * x * x;
    float y = 0.7978845608028654f * (x + 0.044715f * x3);
    float e = __expf(2.f * y);
    float t = 1.f - 2.f / (e + 1.f);   // tanh(y), safe at +/-inf
    return 0.5f * x * (1.f + t);
}

#define SEQ 2048
#define DIMC 768
#define NHEAD 12
#define QKVC 2304
#define LRc 0.1f

// ---------------- fp32 -> bf16 cast ----------------
__global__ __launch_bounds__(256) void cast_f2b_kernel(
    const float* __restrict__ src, u16* __restrict__ dst, int n)
{
    int i = (blockIdx.x * 256 + threadIdx.x) * 4;
    if (i + 3 < n) {
        float4 v = *(const float4*)(src + i);
        dst[i + 0] = f2bf(v.x);
        dst[i + 1] = f2bf(v.y);
        dst[i + 2] = f2bf(v.z);
        dst[i + 3] = f2bf(v.w);
    }
}

// dual cast: z=0 -> (s0,d0), z=1 -> (s1,d1); n elements each
__global__ __launch_bounds__(256) void cast2_f2b_kernel(
    const float* __restrict__ s0, u16* __restrict__ d0,
    const float* __restrict__ s1, u16* __restrict__ d1, int n)
{
    const float* s = blockIdx.z ? s1 : s0;
    u16* d = blockIdx.z ? d1 : d0;
    int i = (blockIdx.x * 256 + threadIdx.x) * 4;
    if (i + 3 < n) {
        float4 v = *(const float4*)(s + i);
        d[i + 0] = f2bf(v.x);
        d[i + 1] = f2bf(v.y);
        d[i + 2] = f2bf(v.z);
        d[i + 3] = f2bf(v.w);
    }
}

// ---------------- fp32 -> (bf16 hi, bf16 lo) split cast ----------------
__global__ __launch_bounds__(256) void cast_split_kernel(
    const float* __restrict__ src, u16* __restrict__ hi, u16* __restrict__ lo, int n)
{
    int i = (blockIdx.x * 256 + threadIdx.x) * 4;
    if (i + 3 < n) {
        float4 v = *(const float4*)(src + i);
        float vv[4] = {v.x, v.y, v.z, v.w};
        #pragma unroll
        for (int j = 0; j < 4; ++j) {
            u16 h = f2bf(vv[j]);
            hi[i + j] = h;
            lo[i + j] = f2bf(vv[j] - bf2f(h));
        }
    }
}

// ---------------- 128x128 LDS-tiled MFMA GEMM body (register staging, R5-proven) ----------------
// mode 0: outb=bf16(C); 1: outf=oscale*C; 2: outf+=oscale*C; 3: atomicAdd(outf, oscale*C)
__device__ __forceinline__ void gemm128_body(
    const u16* __restrict__ A, const u16* __restrict__ W,
    const float* __restrict__ bias, u16* __restrict__ outb, float* __restrict__ outf,
    int N, int Kloop, int Kstride, int act, int mode, float oscale)
{
    __shared__ u16 As[128 * 32];
    __shared__ u16 Bs[128 * 32];
    const int tid  = threadIdx.x;
    const int lane = tid & 63;
    const int wv   = tid >> 6;
    const int r16  = lane & 15;
    const int quad = lane >> 4;
    const int mh   = (wv & 1) * 64;
    const int nh   = (wv >> 1) * 64;
    const int m_blk = blockIdx.x * 128;
    const int n_blk = blockIdx.y * 128;

    const int c0 = tid, c1 = tid + 256;
    const u16* Ag0 = A + (size_t)(m_blk + (c0 >> 2)) * Kstride + (c0 & 3) * 8;
    const u16* Ag1 = A + (size_t)(m_blk + (c1 >> 2)) * Kstride + (c1 & 3) * 8;
    const u16* Wg0 = W + (size_t)(n_blk + (c0 >> 2)) * Kstride + (c0 & 3) * 8;
    const u16* Wg1 = W + (size_t)(n_blk + (c1 >> 2)) * Kstride + (c1 & 3) * 8;
    u16* As0 = As + c0 * 8;
    u16* As1 = As + c1 * 8;
    u16* Bs0 = Bs + c0 * 8;
    u16* Bs1 = Bs + c1 * 8;

    f4v acc[4][4];
    #pragma unroll
    for (int i = 0; i < 4; ++i)
        #pragma unroll
        for (int j = 0; j < 4; ++j) acc[i][j] = (f4v){0.f, 0.f, 0.f, 0.f};

    bf8v av0 = *(const bf8v*)Ag0;
    bf8v av1 = *(const bf8v*)Ag1;
    bf8v bv0 = *(const bf8v*)Wg0;
    bf8v bv1 = *(const bf8v*)Wg1;
    for (int k0 = 0; k0 < Kloop; k0 += 32) {
        __syncthreads();
        *(bf8v*)As0 = av0;
        *(bf8v*)As1 = av1;
        *(bf8v*)Bs0 = bv0;
        *(bf8v*)Bs1 = bv1;
        __syncthreads();
        if (k0 + 32 < Kloop) {
            av0 = *(const bf8v*)(Ag0 + k0 + 32);
            av1 = *(const bf8v*)(Ag1 + k0 + 32);
            bv0 = *(const bf8v*)(Wg0 + k0 + 32);
            bv1 = *(const bf8v*)(Wg1 + k0 + 32);
        }
        bf8v af[4], bfj[4];
        #pragma unroll
        for (int i = 0; i < 4; ++i)
            af[i] = *(const bf8v*)(As + (mh + i * 16 + r16) * 32 + quad * 8);
        #pragma unroll
        for (int j = 0; j < 4; ++j)
            bfj[j] = *(const bf8v*)(Bs + (nh + j * 16 + r16) * 32 + quad * 8);
        #pragma unroll
        for (int i = 0; i < 4; ++i)
            #pragma unroll
            for (int j = 0; j < 4; ++j)
                acc[i][j] = __builtin_amdgcn_mfma_f32_16x16x32_bf16(af[i], bfj[j], acc[i][j], 0, 0, 0);
    }

    #pragma unroll
    for (int j = 0; j < 4; ++j) {
        int gn = n_blk + nh + j * 16 + r16;
        float bvv = bias ? bias[gn] : 0.f;
        #pragma unroll
        for (int i = 0; i < 4; ++i) {
            #pragma unroll
            for (int rr = 0; rr < 4; ++rr) {
                int gm = m_blk + mh + i * 16 + quad * 4 + rr;
                float v = acc[i][j][rr] + bvv;
                if (act == 1) v = gelu_tanh(v);
                else if (act == 2) v = 1.f / (1.f + __expf(-v));
                size_t oi = (size_t)gm * N + gn;
                if (mode == 0) outb[oi] = f2bf(v);
                else if (mode == 1) outf[oi] = oscale * v;
                else if (mode == 2) outf[oi] += oscale * v;
                else atomicAdd(outf + oi, oscale * v);
            }
        }
    }
}

__global__ __launch_bounds__(256) void gemm128_kernel(
    const u16* __restrict__ A, const u16* __restrict__ W,
    const float* __restrict__ bias, u16* __restrict__ outb, float* __restrict__ outf,
    int N, int K, int act, int mode, float oscale)
{
    gemm128_body(A, W, bias, outb, outf, N, K, K, act, mode, oscale);
}

// dual: z=0 -> set0, z=1 -> set1 (both mode 0, act 0, same N/K)
__global__ __launch_bounds__(256) void gemm128_dual_kernel(
    const u16* __restrict__ A0, const u16* __restrict__ W0,
    const float* __restrict__ b0, u16* __restrict__ o0,
    const u16* __restrict__ A1, const u16* __restrict__ W1,
    const float* __restrict__ b1, u16* __restrict__ o1,
    int N, int K)
{
    if (blockIdx.z == 0) gemm128_body(A0, W0, b0, o0, nullptr, N, K, K, 0, 0, 0.f);
    else                 gemm128_body(A1, W1, b1, o1, nullptr, N, K, K, 0, 0, 0.f);
}

// K-split accumulating gemm: z = K-chunk; atomicAdd into pre-zeroed outf.
__global__ __launch_bounds__(256) void gemm128_ksplit_kernel(
    const u16* __restrict__ A, const u16* __restrict__ W,
    const float* __restrict__ bias, float* __restrict__ outf,
    int N, int Kstride, int KC, float oscale)
{
    const int z = blockIdx.z;
    gemm128_body(A + (size_t)z * KC, W + (size_t)z * KC, z == 0 ? bias : nullptr,
                 nullptr, outf, N, KC, Kstride, 0, 3, oscale);
}

// ---------------- split-precision MFMA GEMM (~fp32 quality), 64x64, dual-z ----------------
__global__ __launch_bounds__(256) void gemm_split_kernel(
    const u16* __restrict__ Ahi, const u16* __restrict__ Alo,
    const u16* __restrict__ W0hi, const u16* __restrict__ W0lo, float* __restrict__ out0,
    const u16* __restrict__ W1hi, const u16* __restrict__ W1lo, float* __restrict__ out1,
    int M, int N, int K)
{
    const u16* Whi = blockIdx.z ? W1hi : W0hi;
    const u16* Wlo = blockIdx.z ? W1lo : W0lo;
    float* outf    = blockIdx.z ? out1 : out0;

    const int lane = threadIdx.x & 63;
    const int wv   = threadIdx.x >> 6;
    const int m0   = blockIdx.x * 64 + wv * 16;
    const int n0   = blockIdx.y * 64;
    const int r16  = lane & 15;
    const int quad = lane >> 4;

    const size_t arow = (size_t)(m0 + r16) * K + quad * 8;
    const size_t wrow = (size_t)(n0 + r16) * K + quad * 8;
    const size_t wstride = (size_t)16 * K;

    f4v acc[4];
    #pragma unroll
    for (int j = 0; j < 4; ++j) acc[j] = (f4v){0.f, 0.f, 0.f, 0.f};

    for (int k0 = 0; k0 < K; k0 += 32) {
        bf8v ah = *(const bf8v*)(Ahi + arow + k0);
        bf8v al = *(const bf8v*)(Alo + arow + k0);
        #pragma unroll
        for (int j = 0; j < 4; ++j) {
            bf8v bh = *(const bf8v*)(Whi + wrow + j * wstride + k0);
            bf8v bl = *(const bf8v*)(Wlo + wrow + j * wstride + k0);
            acc[j] = __builtin_amdgcn_mfma_f32_16x16x32_bf16(ah, bh, acc[j], 0, 0, 0);
            acc[j] = __builtin_amdgcn_mfma_f32_16x16x32_bf16(ah, bl, acc[j], 0, 0, 0);
            acc[j] = __builtin_amdgcn_mfma_f32_16x16x32_bf16(al, bh, acc[j], 0, 0, 0);
        }
    }

    #pragma unroll
    for (int j = 0; j < 4; ++j) {
        int gn = n0 + j * 16 + r16;
        #pragma unroll
        for (int rr = 0; rr < 4; ++rr) {
            int gm = m0 + quad * 4 + rr;
            outf[(size_t)gm * N + gn] = acc[j][rr];
        }
    }
}

// ---------------- sliding-window attention (MFMA) ----------------
#define NJ 527
#define NJP 548
__global__ __launch_bounds__(256) void attn_kernel(
    const u16* __restrict__ qkv, u16* __restrict__ outp)
{
    const int bh = blockIdx.y;
    const int b = bh / NHEAD, h = bh % NHEAD;
    const int q0 = blockIdx.x * 16;
    const int jbase = q0 - 511;
    const int tid = threadIdx.x;
    const int lane = tid & 63;
    const int wv = tid >> 6;
    const int r16 = lane & 15;
    const int quad = lane >> 4;

    __shared__ float ss[16][NJP];
    __shared__ float redbuf[16][17];
    __shared__ float rowmax[16];
    __shared__ float rowinv[16];

    const size_t qrow = (size_t)(b * SEQ + q0 + r16) * QKVC + h * 64 + quad * 8;
    bf8v qf0 = *(const bf8v*)(qkv + qrow);
    bf8v qf1 = *(const bf8v*)(qkv + qrow + 32);

    for (int jt = wv; jt < 33; jt += 4) {
        int js_l = jt * 16 + r16;
        int j = jbase + js_l;
        int jc = j & (SEQ - 1);
        const u16* kp = qkv + (size_t)(b * SEQ + jc) * QKVC + DIMC + h * 64 + quad * 8;
        bf8v kf0 = *(const bf8v*)kp;
        bf8v kf1 = *(const bf8v*)(kp + 32);
        f4v acc = (f4v){0.f, 0.f, 0.f, 0.f};
        acc = __builtin_amdgcn_mfma_f32_16x16x32_bf16(qf0, kf0, acc, 0, 0, 0);
        acc = __builtin_amdgcn_mfma_f32_16x16x32_bf16(qf1, kf1, acc, 0, 0, 0);
        if (js_l < NJ) {
            #pragma unroll
            for (int rr = 0; rr < 4; ++rr) {
                int row = quad * 4 + rr;
                bool ok = (j >= 0) && (js_l >= row) && (js_l <= row + 511);
                ss[row][js_l] = ok ? 0.125f * acc[rr] : -1e30f;
            }
        }
    }
    for (int t = tid; t < 16 * 17; t += 256)
        ss[t / 17][527 + t % 17] = 0.f;
    __syncthreads();

    {
        int r = tid >> 4, l16 = tid & 15;
        float mx = -1e30f;
        #pragma unroll 1
        for (int js = l16; js < NJ; js += 16) mx = fmaxf(mx, ss[r][js]);
        redbuf[r][l16] = mx;
        __syncthreads();
        if (l16 == 0) {
            float m = -1e30f;
            #pragma unroll
            for (int i = 0; i < 16; ++i) m = fmaxf(m, redbuf[r][i]);
            rowmax[r] = m;
        }
        __syncthreads();
        float rm = rowmax[r];
        float sm = 0.f;
        #pragma unroll 1
        for (int js = l16; js < NJ; js += 16) {
            float p = __expf(ss[r][js] - rm);
            ss[r][js] = p;
            sm += p;
        }
        redbuf[r][l16] = sm;
        __syncthreads();
        if (l16 == 0) {
            float s = 0.f;
            #pragma unroll
            for (int i = 0; i < 16; ++i) s += redbuf[r][i];
            rowinv[r] = 1.f / s;
        }
        __syncthreads();
    }

    {
        const int d0 = wv * 16;
        const u16* vp = qkv + (size_t)b * SEQ * QKVC + 2 * DIMC + h * 64 + d0 + r16;
        f4v oacc = (f4v){0.f, 0.f, 0.f, 0.f};
        for (int k0 = 0; k0 < 544; k0 += 32) {
            float4 p0 = *(const float4*)&ss[r16][k0 + quad * 8];
            float4 p1 = *(const float4*)&ss[r16][k0 + quad * 8 + 4];
            bf8v pa;
            pa[0] = (short)f2bf(p0.x); pa[1] = (short)f2bf(p0.y);
            pa[2] = (short)f2bf(p0.z); pa[3] = (short)f2bf(p0.w);
            pa[4] = (short)f2bf(p1.x); pa[5] = (short)f2bf(p1.y);
            pa[6] = (short)f2bf(p1.z); pa[7] = (short)f2bf(p1.w);
            bf8v vb;
            #pragma unroll
            for (int m = 0; m < 8; ++m) {
                int j = jbase + k0 + quad * 8 + m;
                int jc = j & (SEQ - 1);
                vb[m] = (short)vp[(size_t)jc * QKVC];
            }
            oacc = __builtin_amdgcn_mfma_f32_16x16x32_bf16(pa, vb, oacc, 0, 0, 0);
        }
        #pragma unroll
        for (int rr = 0; rr < 4; ++rr) {
            int row = quad * 4 + rr;
            size_t oi = (size_t)(b * SEQ + q0 + row) * DIMC + h * 64 + d0 + r16;
            outp[oi] = f2bf(oacc[rr] * rowinv[row]);
        }
    }
}

// ---------------- residual + LayerNorm ----------------
__global__ __launch_bounds__(256) void ln_res_kernel(
    const void* __restrict__ xv, int xf32, const void* __restrict__ yv, int yf32,
    const float* __restrict__ g, const float* __restrict__ be,
    u16* __restrict__ outb, float* __restrict__ outf, int ldout)
{
    const int row = blockIdx.x;
    const int t = threadIdx.x;
    const size_t base = (size_t)row * DIMC;
    float vv[3];
    float s = 0.f, s2 = 0.f;
    #pragma unroll
    for (int i = 0; i < 3; ++i) {
        int d = t + i * 256;
        float a = xf32 ? ((const float*)xv)[base + d] : bf2f(((const u16*)xv)[base + d]);
        float y = yf32 ? ((const float*)yv)[base + d] : bf2f(((const u16*)yv)[base + d]);
        float w = a + y;
        vv[i] = w;
        s += w;
        s2 += w * w;
    }
    #pragma unroll
    for (int o = 32; o > 0; o >>= 1) {
        s  += __shfl_down(s, o);
        s2 += __shfl_down(s2, o);
    }
    __shared__ float rs[4], rq[4], mb[2];
    if ((t & 63) == 0) { rs[t >> 6] = s; rq[t >> 6] = s2; }
    __syncthreads();
    if (t == 0) {
        float S1 = rs[0] + rs[1] + rs[2] + rs[3];
        float S2 = rq[0] + rq[1] + rq[2] + rq[3];
        float mean = S1 * (1.f / 768.f);
        float var = S2 * (1.f / 768.f) - mean * mean;
        mb[0] = mean;
        mb[1] = rsqrtf(var + 1e-5f);
    }
    __syncthreads();
    float mean = mb[0], rstd = mb[1];
    #pragma unroll
    for (int i = 0; i < 3; ++i) {
        int d = t + i * 256;
        float v = (vv[i] - mean) * rstd * g[d] + be[d];
        if (outb) outb[(size_t)row * ldout + d] = f2bf(v);
        else      outf[(size_t)row * ldout + d] = v;
    }
}

// merged LN for x_local / x_global
__global__ __launch_bounds__(256) void ln_res2_kernel(
    const float* __restrict__ x,
    const u16* __restrict__ y0, const float* __restrict__ g0, const float* __restrict__ b0,
    u16* __restrict__ o0,
    const u16* __restrict__ y1, const float* __restrict__ g1, const float* __restrict__ b1,
    u16* __restrict__ o1, int M)
{
    int row = blockIdx.x;
    const u16* y; const float* g; const float* be; u16* ob;
    if (row < M) { y = y0; g = g0; be = b0; ob = o0; }
    else { row -= M; y = y1; g = g1; be = b1; ob = o1; }
    const int t = threadIdx.x;
    const size_t base = (size_t)row * DIMC;
    float vv[3];
    float s = 0.f, s2 = 0.f;
    #pragma unroll
    for (int i = 0; i < 3; ++i) {
        int d = t + i * 256;
        float w = x[base + d] + bf2f(y[base + d]);
        vv[i] = w;
        s += w;
        s2 += w * w;
    }
    #pragma unroll
    for (int o = 32; o > 0; o >>= 1) {
        s  += __shfl_down(s, o);
        s2 += __shfl_down(s2, o);
    }
    __shared__ float rs[4], rq[4], mb[2];
    if ((t & 63) == 0) { rs[t >> 6] = s; rq[t >> 6] = s2; }
    __syncthreads();
    if (t == 0) {
        float S1 = rs[0] + rs[1] + rs[2] + rs[3];
        float S2 = rq[0] + rq[1] + rq[2] + rq[3];
        float mean = S1 * (1.f / 768.f);
        float var = S2 * (1.f / 768.f) - mean * mean;
        mb[0] = mean;
        mb[1] = rsqrtf(var + 1e-5f);
    }
    __syncthreads();
    float mean = mb[0], rstd = mb[1];
    #pragma unroll
    for (int i = 0; i < 3; ++i) {
        int d = t + i * 256;
        float v = (vv[i] - mean) * rstd * g[d] + be[d];
        ob[(size_t)row * 1536 + d] = f2bf(v);
    }
}

// ---------------- chunked delta-rule scan ----------------
__global__ __launch_bounds__(64) void scanA_kernel(
    const u16* __restrict__ tq, const float* __restrict__ tk,
    float* __restrict__ Tm, float* __restrict__ Sm)
{
    const int bid = blockIdx.x;          // 24*32
    const int bh = bid >> 5, c = bid & 31;
    const int b = bh / NHEAD, h = bh % NHEAD;
    const int lane = threadIdx.x;

    __shared__ float Ks[64][68];
    __shared__ float As[64][68];     // A, later reused for S
    __shared__ float Ts[64][68];
    __shared__ u16   Qs[64][72];

    const size_t rowb = (size_t)b * SEQ * DIMC + h * 64;
    const int rg = lane >> 4, c4 = (lane & 15) * 4;
    #pragma unroll 4
    for (int i = 0; i < 16; ++i) {
        int row = i * 4 + rg;
        size_t g = rowb + (size_t)(c * 64 + row) * DIMC + c4;
        *(float4*)&Ks[row][c4] = *(const float4*)(tk + g);
        *(bf4v*)&Qs[row][c4]   = *(const bf4v*)(tq + g);
    }
    __syncthreads();

    float4 kr4[16];
    #pragma unroll
    for (int d4 = 0; d4 < 16; ++d4) kr4[d4] = *(float4*)&Ks[lane][d4 * 4];

    for (int t = 0; t < 64; ++t) {
        float a = 0.f;
        #pragma unroll
        for (int d4 = 0; d4 < 16; ++d4) {
            float4 kt = *(float4*)&Ks[t][d4 * 4];
            a += kt.x * kr4[d4].x + kt.y * kr4[d4].y + kt.z * kr4[d4].z + kt.w * kr4[d4].w;
        }
        As[t][lane] = (lane < t) ? LRc * a : 0.f;
    }
    Ts[0][lane] = (lane == 0) ? 1.f : 0.f;
    for (int t = 1; t < 64; ++t) {
        float s = (lane == t) ? 1.f : 0.f;
        for (int tau = 0; tau < t; ++tau)
            s -= As[t][tau] * Ts[tau][lane];
        Ts[t][lane] = s;
    }
    for (int t = 0; t < 64; ++t) {
        float a = 0.f;
        #pragma unroll
        for (int d4 = 0; d4 < 16; ++d4) {
            bf4v qt = *(bf4v*)&Qs[t][d4 * 4];
            a += bf2f((u16)qt[0]) * kr4[d4].x + bf2f((u16)qt[1]) * kr4[d4].y
               + bf2f((u16)qt[2]) * kr4[d4].z + bf2f((u16)qt[3]) * kr4[d4].w;
        }
        As[t][lane] = (lane <= t) ? a : 0.f;
    }
    __syncthreads();
    float* Tg = Tm + (size_t)bid * 4096;
    float* Sg = Sm + (size_t)bid * 4096;
    #pragma unroll 4
    for (int i = 0; i < 16; ++i) {
        int row = i * 4 + rg;
        *(float4*)(Tg + row * 64 + c4) = *(float4*)&Ts[row][c4];
        *(float4*)(Sg + row * 64 + c4) = *(float4*)&As[row][c4];
    }
}

// scanB: 96 blocks = 24 bh x 4 e-groups; K/Q staging software-pipelined one
// chunk ahead (loads issued after sync1, consumed as LDS writes after sync4).
__global__ __launch_bounds__(256) void scanB_kernel(
    const u16* __restrict__ tq, const float* __restrict__ tk, const float* __restrict__ tv,
    const float* __restrict__ Tm, const float* __restrict__ Sm,
    u16* __restrict__ tito, float* __restrict__ mout)
{
    const int bid = blockIdx.x;          // 96
    const int bh = bid >> 2, eh = bid & 3;
    const int b = bh / NHEAD, h = bh % NHEAD;
    const int tid = threadIdx.x;
    const int tx = tid & 3;
    const int r  = tid >> 2;
    const int cc4 = tx * 4;
    const int e0 = eh * 16;

    __shared__ float Ms[64][20];
    __shared__ float Ys[64][20];
    __shared__ float Us[64][20];
    __shared__ float XK[64][68];
    __shared__ float XT[64][68];
    __shared__ float XS[64][68];
    __shared__ u16   Qt[64][72];

    const size_t rowb = (size_t)b * SEQ * DIMC + h * 64;

    for (int i = tid; i < 64 * 20; i += 256) (&Ms[0][0])[i] = 0.f;

    const int srow = tid & 63;
    const int scc  = (tid >> 6) * 16;

    // prologue: prefetch chunk 0's K/Q into registers
    float4 pk0, pk1, pk2, pk3;
    bf8v pq0, pq1;
    {
        const float* kp = tk + rowb + (size_t)srow * DIMC + scc;
        pk0 = *(const float4*)(kp + 0);  pk1 = *(const float4*)(kp + 4);
        pk2 = *(const float4*)(kp + 8);  pk3 = *(const float4*)(kp + 12);
        const u16* qp = tq + rowb + (size_t)srow * DIMC + scc;
        pq0 = *(const bf8v*)(qp);  pq1 = *(const bf8v*)(qp + 8);
    }

    for (int ch = 0; ch < 32; ++ch) {
        const size_t crow = rowb + (size_t)ch * 64 * DIMC;
        // ---- write K^T -> XK, Q^T -> Qt from prefetched registers ----
        {
            float av[16] = {pk0.x, pk0.y, pk0.z, pk0.w, pk1.x, pk1.y, pk1.z, pk1.w,
                            pk2.x, pk2.y, pk2.z, pk2.w, pk3.x, pk3.y, pk3.z, pk3.w};
            #pragma unroll
            for (int j = 0; j < 16; ++j) XK[scc + j][srow] = av[j];
            #pragma unroll
            for (int j = 0; j < 8; ++j) {
                Qt[scc + j][srow]     = (u16)pq0[j];
                Qt[scc + 8 + j][srow] = (u16)pq1[j];
            }
        }
        __syncthreads();                 // sync 1

        // ---- issue T,V loads (this chunk) + K/Q prefetch (next chunk) ----
        const float* tsrc = Tm + ((size_t)(bh * 32 + ch)) * 4096 + (size_t)srow * 64 + scc;
        float4 t0 = *(const float4*)(tsrc + 0), t1 = *(const float4*)(tsrc + 4),
               t2 = *(const float4*)(tsrc + 8), t3 = *(const float4*)(tsrc + 12);
        float4 v0 = *(const float4*)(tv + crow + (size_t)r * DIMC + e0 + cc4);
        {
            const int chn = (ch + 1 < 32) ? ch + 1 : 31;
            const float* kp = tk + rowb + (size_t)chn * 64 * DIMC + (size_t)srow * DIMC + scc;
            pk0 = *(const float4*)(kp + 0);  pk1 = *(const float4*)(kp + 4);
            pk2 = *(const float4*)(kp + 8);  pk3 = *(const float4*)(kp + 12);
            const u16* qp = tq + rowb + (size_t)chn * 64 * DIMC + (size_t)srow * DIMC + scc;
            pq0 = *(const bf8v*)(qp);  pq1 = *(const bf8v*)(qp + 8);
        }

        // ---- loop 1: P1 = K*M0, O1 = Q*M0 ----
        float p[4] = {0.f, 0.f, 0.f, 0.f};
        float oa[4] = {0.f, 0.f, 0.f, 0.f};
        #pragma unroll 4
        for (int k = 0; k < 64; ++k) {
            float a = XK[k][r];
            float q = bf2f(Qt[k][r]);
            float4 m = *(float4*)&Ms[k][cc4];
            p[0] += a * m.x; p[1] += a * m.y; p[2] += a * m.z; p[3] += a * m.w;
            oa[0] += q * m.x; oa[1] += q * m.y; oa[2] += q * m.z; oa[3] += q * m.w;
        }
        {
            float av[16] = {t0.x, t0.y, t0.z, t0.w, t1.x, t1.y, t1.z, t1.w,
                            t2.x, t2.y, t2.z, t2.w, t3.x, t3.y, t3.z, t3.w};
            #pragma unroll
            for (int j = 0; j < 16; ++j) XT[scc + j][srow] = av[j];
            Ys[r][cc4 + 0] = LRc * (v0.x - p[0]);
            Ys[r][cc4 + 1] = LRc * (v0.y - p[1]);
            Ys[r][cc4 + 2] = LRc * (v0.z - p[2]);
            Ys[r][cc4 + 3] = LRc * (v0.w - p[3]);
        }
        __syncthreads();                 // sync 2

        const float* ssrc = Sm + ((size_t)(bh * 32 + ch)) * 4096 + (size_t)srow * 64 + scc;
        float4 s0 = *(const float4*)(ssrc + 0), s1 = *(const float4*)(ssrc + 4),
               s2 = *(const float4*)(ssrc + 8), s3 = *(const float4*)(ssrc + 12);

        // ---- loop 2: U = T*B ----
        float u[4] = {0.f, 0.f, 0.f, 0.f};
        #pragma unroll 4
        for (int k = 0; k < 64; ++k) {
            float a = XT[k][r];
            float4 bb = *(float4*)&Ys[k][cc4];
            u[0] += a * bb.x; u[1] += a * bb.y; u[2] += a * bb.z; u[3] += a * bb.w;
        }
        {
            float av[16] = {s0.x, s0.y, s0.z, s0.w, s1.x, s1.y, s1.z, s1.w,
                            s2.x, s2.y, s2.z, s2.w, s3.x, s3.y, s3.z, s3.w};
            #pragma unroll
            for (int j = 0; j < 16; ++j) XS[scc + j][srow] = av[j];
            #pragma unroll
            for (int j = 0; j < 4; ++j) Us[r][cc4 + j] = u[j];
        }
        __syncthreads();                 // sync 3

        // ---- loop 3 (merged): O2 += S*U ; M += K^T*U ----
        float m0[4];
        #pragma unroll
        for (int j = 0; j < 4; ++j) m0[j] = Ms[r][cc4 + j];
        #pragma unroll 4
        for (int k = 0; k < 64; ++k) {
            float sa = XS[k][r];
            float ka = XK[r][k];
            float4 uu = *(float4*)&Us[k][cc4];
            oa[0] += sa * uu.x; oa[1] += sa * uu.y; oa[2] += sa * uu.z; oa[3] += sa * uu.w;
            m0[0] += ka * uu.x; m0[1] += ka * uu.y; m0[2] += ka * uu.z; m0[3] += ka * uu.w;
        }
        #pragma unroll
        for (int j = 0; j < 4; ++j) Ms[r][cc4 + j] = m0[j];
        {
            u16* op = tito + crow + (size_t)r * DIMC + e0 + cc4;
            bf4v w;
            #pragma unroll
            for (int j = 0; j < 4; ++j) w[j] = (short)f2bf(oa[j]);
            *(bf4v*)op = w;
        }
        __syncthreads();                 // sync 4 (M visible; XK/Qt free for overwrite)
    }
    {
        float* mg = mout + (size_t)bh * 4096 + (size_t)r * 64 + e0 + cc4;
        *(float4*)mg = *(float4*)&Ms[r][cc4];
    }
}

// ---------------- gated combine ----------------
__global__ __launch_bounds__(768) void combine_kernel(
    const u16* __restrict__ xlg, const u16* __restrict__ gate, u16* __restrict__ xc)
{
    const int row = blockIdx.x;
    const int t = threadIdx.x;
    float g = bf2f(gate[(size_t)row * DIMC + t]);
    float xl = bf2f(xlg[(size_t)row * 1536 + t]);
    float xg = bf2f(xlg[(size_t)row * 1536 + 768 + t]);
    xc[(size_t)row * DIMC + t] = f2bf(g * xl + (1.f - g) * xg);
}

// ---------------- launcher ----------------
extern "C" void kernel_launch(void* const* d_in, const int* in_sizes, int n_in,
                              void* d_out, int out_size, void* d_ws, size_t ws_size,
                              hipStream_t stream) {
    const float* x          = (const float*)d_in[0];
    const float* in_proj_w  = (const float*)d_in[1];
    const float* in_proj_b  = (const float*)d_in[2];
    const float* out_proj_w = (const float*)d_in[3];
    const float* out_proj_b = (const float*)d_in[4];
    const float* ln_local_g = (const float*)d_in[5];
    const float* ln_local_b = (const float*)d_in[6];
    const float* t_wq       = (const float*)d_in[7];
    const float* t_wk       = (const float*)d_in[8];
    const float* t_wv       = (const float*)d_in[9];
    const float* t_wo       = (const float*)d_in[10];
    const float* ln_tit_g   = (const float*)d_in[11];
    const float* ln_tit_b   = (const float*)d_in[12];
    const float* gate_w     = (const float*)d_in[13];
    const float* gate_b     = (const float*)d_in[14];
    const float* cms_w1     = (const float*)d_in[15];
    const float* cms_b1     = (const float*)d_in[16];
    const float* cms_w2     = (const float*)d_in[17];
    const float* cms_b2     = (const float*)d_in[18];
    const float* ln_cms_g   = (const float*)d_in[19];
    const float* ln_cms_b   = (const float*)d_in[20];

    const int Mrows = 2 * SEQ;  // 4096

    // ---- workspace (u16 offsets), cap 37,748,736 u16 = 75,497,472 B ----
    u16* ws = (u16*)d_ws;
    u16*   qkv   = ws + 0;
    u16*   lout  = ws + 0;
    u16*   gout  = ws + 3145728;
    u16*   gact  = ws + 6291456;
    u16*   tq16  = ws + 9437184;
    u16*   wB    = ws + 9437184;      // 768x768 bf16 (589824)
    u16*   wB2   = ws + 10027008;     // second weight slot (t_wo)
    u16*   w_inp = ws + 12582912;
    float* tkf   = (float*)(ws + 12582912);
    u16*   W1S   = ws + 12582912;
    u16*   W2S   = ws + 14942208;
    float* tvf   = (float*)(ws + 18874368);
    u16*   w_tqb = ws + 25165824;
    u16*   tito  = ws + 25165824;
    u16*   w_hi  = ws + 28311552;
    u16*   w_lo  = ws + 28901376;
    u16*   w_hi2 = ws + 29491200;
    u16*   w_lo2 = ws + 30081024;
    u16*   attn_o= ws + 28311552;
    u16*   xc    = ws + 28311552;
    u16*   x_hi  = ws + 31457280;
    u16*   x_lo  = ws + 34603008;
    u16*   xlg   = ws + 31457280;
    u16*   h     = ws + 0;            // CMS h: A+B regions dead after combine

    float* out32 = (float*)d_out;
    float* cmsacc = out32;
    float* mout  = out32 + (size_t)Mrows * DIMC;

    float* Tmat = (float*)(ws + 31457280);   // G region (exact fit)
    float* Smat = out32;                     // cmsacc region as scratch pre-CMS

    auto cast = [&](const float* src, u16* dst, int n) {
        cast_f2b_kernel<<<(n + 1023) / 1024, 256, 0, stream>>>(src, dst, n);
    };
    auto gemm = [&](const u16* A, const u16* W, const float* bias, u16* ob, float* of,
                    int M, int N, int K, int act, int mode, float oscale) {
        gemm128_kernel<<<dim3(M / 128, N / 128), 256, 0, stream>>>(
            A, W, bias, ob, of, N, K, act, mode, oscale);
    };
    auto split = [&](const float* src, u16* hi, u16* lo, int n) {
        cast_split_kernel<<<(n + 1023) / 1024, 256, 0, stream>>>(src, hi, lo, n);
    };

    // 1. split-cast x
    split(x, x_hi, x_lo, Mrows * DIMC);
    // 2. qkv projection
    cast(in_proj_w, w_inp, QKVC * DIMC);
    gemm(x_hi, w_inp, in_proj_b, qkv, nullptr, Mrows, QKVC, DIMC, 0, 0, 0.f);
    // 3+4. tk & tv split-precision in ONE dual launch
    split(t_wk, w_hi, w_lo, DIMC * DIMC);
    split(t_wv, w_hi2, w_lo2, DIMC * DIMC);
    gemm_split_kernel<<<dim3(Mrows / 64, DIMC / 64, 2), 256, 0, stream>>>(
        x_hi, x_lo, w_hi, w_lo, tkf, w_hi2, w_lo2, tvf, Mrows, DIMC, DIMC);
    // 5. tq (bf16)
    cast(t_wq, w_tqb, DIMC * DIMC);
    gemm(x_hi, w_tqb, nullptr, tq16, nullptr, Mrows, DIMC, DIMC, 0, 0, 0.f);
    // 6. sliding-window attention
    attn_kernel<<<dim3(SEQ / 16, 2 * NHEAD), 256, 0, stream>>>(qkv, attn_o);
    // 7. chunked delta-rule scan
    scanA_kernel<<<24 * 32, 64, 0, stream>>>(tq16, tkf, Tmat, Smat);
    scanB_kernel<<<24 * 4, 256, 0, stream>>>(tq16, tkf, tvf, Tmat, Smat, tito, mout);
    // 8+10. out_proj + titans out_proj in ONE dual launch
    cast2_f2b_kernel<<<dim3((DIMC * DIMC + 1023) / 1024, 1, 2), 256, 0, stream>>>(
        out_proj_w, wB, t_wo, wB2, DIMC * DIMC);
    gemm128_dual_kernel<<<dim3(Mrows / 128, DIMC / 128, 2), 256, 0, stream>>>(
        attn_o, wB, out_proj_b, lout, tito, wB2, nullptr, gout, DIMC, DIMC);
    // 9+11. x_local & x_global LayerNorms in ONE launch
    ln_res2_kernel<<<2 * Mrows, 256, 0, stream>>>(
        x, lout, ln_local_g, ln_local_b, xlg,
        gout, ln_tit_g, ln_tit_b, xlg + 768, Mrows);
    // 12. gate
    cast(gate_w, wB, DIMC * 2 * DIMC);
    gemm(xlg, wB, gate_b, gact, nullptr, Mrows, DIMC, 2 * DIMC, 2, 0, 0.f);
    // 13. combine -> xc
    combine_kernel<<<Mrows, 768, 0, stream>>>(xlg, gact, xc);
    // 14. CMS merged over full M; gemm2 K-split x4 with atomicAdd into
    //     pre-zeroed cmsacc (overwrites Smat scratch: scanB done).
    hipMemsetAsync(cmsacc, 0, (size_t)Mrows * DIMC * sizeof(float), stream);
    for (int l = 0; l < 4; ++l) {
        cast2_f2b_kernel<<<dim3((2359296 + 1023) / 1024, 1, 2), 256, 0, stream>>>(
            cms_w1 + (size_t)l * 2359296, W1S, cms_w2 + (size_t)l * 2359296, W2S, 2359296);
        gemm(xc, W1S, cms_b1 + l * 3072, h, nullptr, Mrows, 3072, DIMC, 1, 0, 0.f);
        gemm128_ksplit_kernel<<<dim3(Mrows / 128, DIMC / 128, 4), 256, 0, stream>>>(
            h, W2S, cms_b2 + l * DIMC, cmsacc, DIMC, 3072, 768, 0.25f);
    }
    // 15. final LN -> d_out
    ln_res_kernel<<<Mrows, 256, 0, stream>>>(xc, 0, cmsacc, 1, ln_cms_g, ln_cms_b, nullptr, out32, DIMC);

    (void)in_sizes; (void)n_in; (void)out_size; (void)ws_size;
}

// Round 12
// 1238.523 us; speedup vs baseline: 1.1448x; 1.0409x over previous
//
#include <hip/hip_runtime.h>
#include <hip/hip_bf16.h>
#include <math.h>

// ---------------- common helpers ----------------
typedef unsigned short u16;
typedef __attribute__((ext_vector_type(8))) short bf8v;   // 8 bf16 (4 VGPRs)
typedef __attribute__((ext_vector_type(4))) short bf4v;   // 4 bf16 (8 bytes)
typedef __attribute__((ext_vector_type(4))) float f4v;    // 4 fp32

__device__ __forceinline__ float bf2f(u16 h) {
    unsigned int u = ((unsigned int)h) << 16;
    float f;
    __builtin_memcpy(&f, &u, 4);
    return f;
}
__device__ __forceinline__ u16 f2bf(float f) {
    unsigned int u;
    __builtin_memcpy(&u, &f, 4);
    unsigned int r = (u + 0x7FFFu + ((u >> 16) & 1u)) >> 16;  // RN-even
    return (u16)r;
}
__device__ __forceinline__ float gelu_tanh(float x) {
    float x3 = x * x * x;
    float y = 0.7978845608028654f * (x + 0.044715f * x3);
    float e = __expf(2.f * y);
    float t = 1.f - 2.f / (e + 1.f);   // tanh(y), safe at +/-inf
    return 0.5f * x * (1.f + t);
}

#define SEQ 2048
#define DIMC 768
#define NHEAD 12
#define QKVC 2304
#define LRc 0.1f

// ---------------- fp32 -> bf16 cast ----------------
__global__ __launch_bounds__(256) void cast_f2b_kernel(
    const float* __restrict__ src, u16* __restrict__ dst, int n)
{
    int i = (blockIdx.x * 256 + threadIdx.x) * 4;
    if (i + 3 < n) {
        float4 v = *(const float4*)(src + i);
        dst[i + 0] = f2bf(v.x);
        dst[i + 1] = f2bf(v.y);
        dst[i + 2] = f2bf(v.z);
        dst[i + 3] = f2bf(v.w);
    }
}

// dual cast: z=0 -> (s0,d0), z=1 -> (s1,d1); n elements each
__global__ __launch_bounds__(256) void cast2_f2b_kernel(
    const float* __restrict__ s0, u16* __restrict__ d0,
    const float* __restrict__ s1, u16* __restrict__ d1, int n)
{
    const float* s = blockIdx.z ? s1 : s0;
    u16* d = blockIdx.z ? d1 : d0;
    int i = (blockIdx.x * 256 + threadIdx.x) * 4;
    if (i + 3 < n) {
        float4 v = *(const float4*)(s + i);
        d[i + 0] = f2bf(v.x);
        d[i + 1] = f2bf(v.y);
        d[i + 2] = f2bf(v.z);
        d[i + 3] = f2bf(v.w);
    }
}

// ---------------- fp32 -> (bf16 hi, bf16 lo) split cast ----------------
__global__ __launch_bounds__(256) void cast_split_kernel(
    const float* __restrict__ src, u16* __restrict__ hi, u16* __restrict__ lo, int n)
{
    int i = (blockIdx.x * 256 + threadIdx.x) * 4;
    if (i + 3 < n) {
        float4 v = *(const float4*)(src + i);
        float vv[4] = {v.x, v.y, v.z, v.w};
        #pragma unroll
        for (int j = 0; j < 4; ++j) {
            u16 h = f2bf(vv[j]);
            hi[i + j] = h;
            lo[i + j] = f2bf(vv[j] - bf2f(h));
        }
    }
}

// ---------------- 128x128 LDS-tiled MFMA GEMM body (register staging, R5-proven) ----------------
// mode 0: outb=bf16(C); 1: outf=oscale*C; 2: outf+=oscale*C; 3: atomicAdd(outf, oscale*C)
__device__ __forceinline__ void gemm128_body(
    const u16* __restrict__ A, const u16* __restrict__ W,
    const float* __restrict__ bias, u16* __restrict__ outb, float* __restrict__ outf,
    int N, int Kloop, int Kstride, int act, int mode, float oscale)
{
    __shared__ u16 As[128 * 32];
    __shared__ u16 Bs[128 * 32];
    const int tid  = threadIdx.x;
    const int lane = tid & 63;
    const int wv   = tid >> 6;
    const int r16  = lane & 15;
    const int quad = lane >> 4;
    const int mh   = (wv & 1) * 64;
    const int nh   = (wv >> 1) * 64;
    const int m_blk = blockIdx.x * 128;
    const int n_blk = blockIdx.y * 128;

    const int c0 = tid, c1 = tid + 256;
    const u16* Ag0 = A + (size_t)(m_blk + (c0 >> 2)) * Kstride + (c0 & 3) * 8;
    const u16* Ag1 = A + (size_t)(m_blk + (c1 >> 2)) * Kstride + (c1 & 3) * 8;
    const u16* Wg0 = W + (size_t)(n_blk + (c0 >> 2)) * Kstride + (c0 & 3) * 8;
    const u16* Wg1 = W + (size_t)(n_blk + (c1 >> 2)) * Kstride + (c1 & 3) * 8;
    u16* As0 = As + c0 * 8;
    u16* As1 = As + c1 * 8;
    u16* Bs0 = Bs + c0 * 8;
    u16* Bs1 = Bs + c1 * 8;

    f4v acc[4][4];
    #pragma unroll
    for (int i = 0; i < 4; ++i)
        #pragma unroll
        for (int j = 0; j < 4; ++j) acc[i][j] = (f4v){0.f, 0.f, 0.f, 0.f};

    bf8v av0 = *(const bf8v*)Ag0;
    bf8v av1 = *(const bf8v*)Ag1;
    bf8v bv0 = *(const bf8v*)Wg0;
    bf8v bv1 = *(const bf8v*)Wg1;
    for (int k0 = 0; k0 < Kloop; k0 += 32) {
        __syncthreads();
        *(bf8v*)As0 = av0;
        *(bf8v*)As1 = av1;
        *(bf8v*)Bs0 = bv0;
        *(bf8v*)Bs1 = bv1;
        __syncthreads();
        if (k0 + 32 < Kloop) {
            av0 = *(const bf8v*)(Ag0 + k0 + 32);
            av1 = *(const bf8v*)(Ag1 + k0 + 32);
            bv0 = *(const bf8v*)(Wg0 + k0 + 32);
            bv1 = *(const bf8v*)(Wg1 + k0 + 32);
        }
        bf8v af[4], bfj[4];
        #pragma unroll
        for (int i = 0; i < 4; ++i)
            af[i] = *(const bf8v*)(As + (mh + i * 16 + r16) * 32 + quad * 8);
        #pragma unroll
        for (int j = 0; j < 4; ++j)
            bfj[j] = *(const bf8v*)(Bs + (nh + j * 16 + r16) * 32 + quad * 8);
        #pragma unroll
        for (int i = 0; i < 4; ++i)
            #pragma unroll
            for (int j = 0; j < 4; ++j)
                acc[i][j] = __builtin_amdgcn_mfma_f32_16x16x32_bf16(af[i], bfj[j], acc[i][j], 0, 0, 0);
    }

    #pragma unroll
    for (int j = 0; j < 4; ++j) {
        int gn = n_blk + nh + j * 16 + r16;
        float bvv = bias ? bias[gn] : 0.f;
        #pragma unroll
        for (int i = 0; i < 4; ++i) {
            #pragma unroll
            for (int rr = 0; rr < 4; ++rr) {
                int gm = m_blk + mh + i * 16 + quad * 4 + rr;
                float v = acc[i][j][rr] + bvv;
                if (act == 1) v = gelu_tanh(v);
                else if (act == 2) v = 1.f / (1.f + __expf(-v));
                size_t oi = (size_t)gm * N + gn;
                if (mode == 0) outb[oi] = f2bf(v);
                else if (mode == 1) outf[oi] = oscale * v;
                else if (mode == 2) outf[oi] += oscale * v;
                else atomicAdd(outf + oi, oscale * v);
            }
        }
    }
}

__global__ __launch_bounds__(256) void gemm128_kernel(
    const u16* __restrict__ A, const u16* __restrict__ W,
    const float* __restrict__ bias, u16* __restrict__ outb, float* __restrict__ outf,
    int N, int K, int act, int mode, float oscale)
{
    gemm128_body(A, W, bias, outb, outf, N, K, K, act, mode, oscale);
}

// dual: z=0 -> set0, z=1 -> set1 (both mode 0, act 0, same N/K)
__global__ __launch_bounds__(256) void gemm128_dual_kernel(
    const u16* __restrict__ A0, const u16* __restrict__ W0,
    const float* __restrict__ b0, u16* __restrict__ o0,
    const u16* __restrict__ A1, const u16* __restrict__ W1,
    const float* __restrict__ b1, u16* __restrict__ o1,
    int N, int K)
{
    if (blockIdx.z == 0) gemm128_body(A0, W0, b0, o0, nullptr, N, K, K, 0, 0, 0.f);
    else                 gemm128_body(A1, W1, b1, o1, nullptr, N, K, K, 0, 0, 0.f);
}

// K-split accumulating gemm: z = K-chunk; atomicAdd into pre-zeroed outf.
__global__ __launch_bounds__(256) void gemm128_ksplit_kernel(
    const u16* __restrict__ A, const u16* __restrict__ W,
    const float* __restrict__ bias, float* __restrict__ outf,
    int N, int Kstride, int KC, float oscale)
{
    const int z = blockIdx.z;
    gemm128_body(A + (size_t)z * KC, W + (size_t)z * KC, z == 0 ? bias : nullptr,
                 nullptr, outf, N, KC, Kstride, 0, 3, oscale);
}

// ---------------- split-precision MFMA GEMM (~fp32 quality), 64x64, dual-z ----------------
__global__ __launch_bounds__(256) void gemm_split_kernel(
    const u16* __restrict__ Ahi, const u16* __restrict__ Alo,
    const u16* __restrict__ W0hi, const u16* __restrict__ W0lo, float* __restrict__ out0,
    const u16* __restrict__ W1hi, const u16* __restrict__ W1lo, float* __restrict__ out1,
    int M, int N, int K)
{
    const u16* Whi = blockIdx.z ? W1hi : W0hi;
    const u16* Wlo = blockIdx.z ? W1lo : W0lo;
    float* outf    = blockIdx.z ? out1 : out0;

    const int lane = threadIdx.x & 63;
    const int wv   = threadIdx.x >> 6;
    const int m0   = blockIdx.x * 64 + wv * 16;
    const int n0   = blockIdx.y * 64;
    const int r16  = lane & 15;
    const int quad = lane >> 4;

    const size_t arow = (size_t)(m0 + r16) * K + quad * 8;
    const size_t wrow = (size_t)(n0 + r16) * K + quad * 8;
    const size_t wstride = (size_t)16 * K;

    f4v acc[4];
    #pragma unroll
    for (int j = 0; j < 4; ++j) acc[j] = (f4v){0.f, 0.f, 0.f, 0.f};

    for (int k0 = 0; k0 < K; k0 += 32) {
        bf8v ah = *(const bf8v*)(Ahi + arow + k0);
        bf8v al = *(const bf8v*)(Alo + arow + k0);
        #pragma unroll
        for (int j = 0; j < 4; ++j) {
            bf8v bh = *(const bf8v*)(Whi + wrow + j * wstride + k0);
            bf8v bl = *(const bf8v*)(Wlo + wrow + j * wstride + k0);
            acc[j] = __builtin_amdgcn_mfma_f32_16x16x32_bf16(ah, bh, acc[j], 0, 0, 0);
            acc[j] = __builtin_amdgcn_mfma_f32_16x16x32_bf16(ah, bl, acc[j], 0, 0, 0);
            acc[j] = __builtin_amdgcn_mfma_f32_16x16x32_bf16(al, bh, acc[j], 0, 0, 0);
        }
    }

    #pragma unroll
    for (int j = 0; j < 4; ++j) {
        int gn = n0 + j * 16 + r16;
        #pragma unroll
        for (int rr = 0; rr < 4; ++rr) {
            int gm = m0 + quad * 4 + rr;
            outf[(size_t)gm * N + gn] = acc[j][rr];
        }
    }
}

// ---------------- attention device body (smem-carved) ----------------
#define NJ 527
#define NJP 548
#define SCANB_BLOCKS 96
#define FUSED_SMEM 76800

__device__ void attn_dev(char* smem, int ab, const u16* __restrict__ qkv,
                         u16* __restrict__ outp)
{
    float (*ss)[NJP]   = (float(*)[NJP])(smem);            // 16*548*4 = 35072
    float (*redbuf)[17]= (float(*)[17])(smem + 35072);     // 1088
    float* rowmax      = (float*)(smem + 36160);
    float* rowinv      = (float*)(smem + 36224);

    const int bh = ab >> 7;            // 0..23  (consecutive ab share bh -> L2 locality)
    const int b = bh / NHEAD, h = bh % NHEAD;
    const int q0 = (ab & 127) * 16;
    const int jbase = q0 - 511;
    const int tid = threadIdx.x;
    const int lane = tid & 63;
    const int wv = tid >> 6;
    const int r16 = lane & 15;
    const int quad = lane >> 4;

    const size_t qrow = (size_t)(b * SEQ + q0 + r16) * QKVC + h * 64 + quad * 8;
    bf8v qf0 = *(const bf8v*)(qkv + qrow);
    bf8v qf1 = *(const bf8v*)(qkv + qrow + 32);

    for (int jt = wv; jt < 33; jt += 4) {
        int js_l = jt * 16 + r16;
        int j = jbase + js_l;
        int jc = j & (SEQ - 1);
        const u16* kp = qkv + (size_t)(b * SEQ + jc) * QKVC + DIMC + h * 64 + quad * 8;
        bf8v kf0 = *(const bf8v*)kp;
        bf8v kf1 = *(const bf8v*)(kp + 32);
        f4v acc = (f4v){0.f, 0.f, 0.f, 0.f};
        acc = __builtin_amdgcn_mfma_f32_16x16x32_bf16(qf0, kf0, acc, 0, 0, 0);
        acc = __builtin_amdgcn_mfma_f32_16x16x32_bf16(qf1, kf1, acc, 0, 0, 0);
        if (js_l < NJ) {
            #pragma unroll
            for (int rr = 0; rr < 4; ++rr) {
                int row = quad * 4 + rr;
                bool ok = (j >= 0) && (js_l >= row) && (js_l <= row + 511);
                ss[row][js_l] = ok ? 0.125f * acc[rr] : -1e30f;
            }
        }
    }
    for (int t = tid; t < 16 * 17; t += 256)
        ss[t / 17][527 + t % 17] = 0.f;
    __syncthreads();

    {
        int r = tid >> 4, l16 = tid & 15;
        float mx = -1e30f;
        #pragma unroll 1
        for (int js = l16; js < NJ; js += 16) mx = fmaxf(mx, ss[r][js]);
        redbuf[r][l16] = mx;
        __syncthreads();
        if (l16 == 0) {
            float m = -1e30f;
            #pragma unroll
            for (int i = 0; i < 16; ++i) m = fmaxf(m, redbuf[r][i]);
            rowmax[r] = m;
        }
        __syncthreads();
        float rm = rowmax[r];
        float sm = 0.f;
        #pragma unroll 1
        for (int js = l16; js < NJ; js += 16) {
            float p = __expf(ss[r][js] - rm);
            ss[r][js] = p;
            sm += p;
        }
        redbuf[r][l16] = sm;
        __syncthreads();
        if (l16 == 0) {
            float s = 0.f;
            #pragma unroll
            for (int i = 0; i < 16; ++i) s += redbuf[r][i];
            rowinv[r] = 1.f / s;
        }
        __syncthreads();
    }

    {
        const int d0 = wv * 16;
        const u16* vp = qkv + (size_t)b * SEQ * QKVC + 2 * DIMC + h * 64 + d0 + r16;
        f4v oacc = (f4v){0.f, 0.f, 0.f, 0.f};
        for (int k0 = 0; k0 < 544; k0 += 32) {
            float4 p0 = *(const float4*)&ss[r16][k0 + quad * 8];
            float4 p1 = *(const float4*)&ss[r16][k0 + quad * 8 + 4];
            bf8v pa;
            pa[0] = (short)f2bf(p0.x); pa[1] = (short)f2bf(p0.y);
            pa[2] = (short)f2bf(p0.z); pa[3] = (short)f2bf(p0.w);
            pa[4] = (short)f2bf(p1.x); pa[5] = (short)f2bf(p1.y);
            pa[6] = (short)f2bf(p1.z); pa[7] = (short)f2bf(p1.w);
            bf8v vb;
            #pragma unroll
            for (int m = 0; m < 8; ++m) {
                int j = jbase + k0 + quad * 8 + m;
                int jc = j & (SEQ - 1);
                vb[m] = (short)vp[(size_t)jc * QKVC];
            }
            oacc = __builtin_amdgcn_mfma_f32_16x16x32_bf16(pa, vb, oacc, 0, 0, 0);
        }
        #pragma unroll
        for (int rr = 0; rr < 4; ++rr) {
            int row = quad * 4 + rr;
            size_t oi = (size_t)(b * SEQ + q0 + row) * DIMC + h * 64 + d0 + r16;
            outp[oi] = f2bf(oacc[rr] * rowinv[row]);
        }
    }
}

// ---------------- scanB device body (smem-carved; R7-proven math) ----------------
__device__ void scanB_dev(char* smem, int bid,
    const u16* __restrict__ tq, const float* __restrict__ tk, const float* __restrict__ tv,
    const float* __restrict__ Tm, const float* __restrict__ Sm,
    u16* __restrict__ tito, float* __restrict__ mout)
{
    float (*Ms)[20] = (float(*)[20])(smem);                // 5120
    float (*Ys)[20] = (float(*)[20])(smem + 5120);         // 5120
    float (*Us)[20] = (float(*)[20])(smem + 10240);        // 5120
    float (*XK)[68] = (float(*)[68])(smem + 15360);        // 17408
    float (*XT)[68] = (float(*)[68])(smem + 32768);        // 17408
    float (*XS)[68] = (float(*)[68])(smem + 50176);        // 17408
    u16   (*Qt)[72] = (u16(*)[72])(smem + 67584);          // 9216 -> 76800

    const int bh = bid >> 2, eh = bid & 3;
    const int b = bh / NHEAD, h = bh % NHEAD;
    const int tid = threadIdx.x;
    const int tx = tid & 3;
    const int r  = tid >> 2;
    const int cc4 = tx * 4;
    const int e0 = eh * 16;

    const size_t rowb = (size_t)b * SEQ * DIMC + h * 64;

    for (int i = tid; i < 64 * 20; i += 256) (&Ms[0][0])[i] = 0.f;

    const int srow = tid & 63;
    const int scc  = (tid >> 6) * 16;

    for (int ch = 0; ch < 32; ++ch) {
        const size_t crow = rowb + (size_t)ch * 64 * DIMC;
        {
            const float* s = tk + crow + (size_t)srow * DIMC + scc;
            float4 a0 = *(const float4*)(s + 0), a1 = *(const float4*)(s + 4),
                   a2 = *(const float4*)(s + 8), a3 = *(const float4*)(s + 12);
            float av[16] = {a0.x, a0.y, a0.z, a0.w, a1.x, a1.y, a1.z, a1.w,
                            a2.x, a2.y, a2.z, a2.w, a3.x, a3.y, a3.z, a3.w};
            #pragma unroll
            for (int j = 0; j < 16; ++j) XK[scc + j][srow] = av[j];
            const u16* qg = tq + crow + (size_t)srow * DIMC + scc;
            bf8v q0 = *(const bf8v*)(qg), q1 = *(const bf8v*)(qg + 8);
            #pragma unroll
            for (int j = 0; j < 8; ++j) {
                Qt[scc + j][srow]     = (u16)q0[j];
                Qt[scc + 8 + j][srow] = (u16)q1[j];
            }
        }
        __syncthreads();                 // sync 1

        const float* tsrc = Tm + ((size_t)(bh * 32 + ch)) * 4096 + (size_t)srow * 64 + scc;
        float4 t0 = *(const float4*)(tsrc + 0), t1 = *(const float4*)(tsrc + 4),
               t2 = *(const float4*)(tsrc + 8), t3 = *(const float4*)(tsrc + 12);
        float4 v0 = *(const float4*)(tv + crow + (size_t)r * DIMC + e0 + cc4);

        float p[4] = {0.f, 0.f, 0.f, 0.f};
        float oa[4] = {0.f, 0.f, 0.f, 0.f};
        #pragma unroll 4
        for (int k = 0; k < 64; ++k) {
            float a = XK[k][r];
            float q = bf2f(Qt[k][r]);
            float4 m = *(float4*)&Ms[k][cc4];
            p[0] += a * m.x; p[1] += a * m.y; p[2] += a * m.z; p[3] += a * m.w;
            oa[0] += q * m.x; oa[1] += q * m.y; oa[2] += q * m.z; oa[3] += q * m.w;
        }
        {
            float av[16] = {t0.x, t0.y, t0.z, t0.w, t1.x, t1.y, t1.z, t1.w,
                            t2.x, t2.y, t2.z, t2.w, t3.x, t3.y, t3.z, t3.w};
            #pragma unroll
            for (int j = 0; j < 16; ++j) XT[scc + j][srow] = av[j];
            Ys[r][cc4 + 0] = LRc * (v0.x - p[0]);
            Ys[r][cc4 + 1] = LRc * (v0.y - p[1]);
            Ys[r][cc4 + 2] = LRc * (v0.z - p[2]);
            Ys[r][cc4 + 3] = LRc * (v0.w - p[3]);
        }
        __syncthreads();                 // sync 2

        const float* ssrc = Sm + ((size_t)(bh * 32 + ch)) * 4096 + (size_t)srow * 64 + scc;
        float4 s0 = *(const float4*)(ssrc + 0), s1 = *(const float4*)(ssrc + 4),
               s2 = *(const float4*)(ssrc + 8), s3 = *(const float4*)(ssrc + 12);

        float u[4] = {0.f, 0.f, 0.f, 0.f};
        #pragma unroll 4
        for (int k = 0; k < 64; ++k) {
            float a = XT[k][r];
            float4 bb = *(float4*)&Ys[k][cc4];
            u[0] += a * bb.x; u[1] += a * bb.y; u[2] += a * bb.z; u[3] += a * bb.w;
        }
        {
            float av[16] = {s0.x, s0.y, s0.z, s0.w, s1.x, s1.y, s1.z, s1.w,
                            s2.x, s2.y, s2.z, s2.w, s3.x, s3.y, s3.z, s3.w};
            #pragma unroll
            for (int j = 0; j < 16; ++j) XS[scc + j][srow] = av[j];
            #pragma unroll
            for (int j = 0; j < 4; ++j) Us[r][cc4 + j] = u[j];
        }
        __syncthreads();                 // sync 3

        float m0[4];
        #pragma unroll
        for (int j = 0; j < 4; ++j) m0[j] = Ms[r][cc4 + j];
        #pragma unroll 4
        for (int k = 0; k < 64; ++k) {
            float sa = XS[k][r];
            float ka = XK[r][k];
            float4 uu = *(float4*)&Us[k][cc4];
            oa[0] += sa * uu.x; oa[1] += sa * uu.y; oa[2] += sa * uu.z; oa[3] += sa * uu.w;
            m0[0] += ka * uu.x; m0[1] += ka * uu.y; m0[2] += ka * uu.z; m0[3] += ka * uu.w;
        }
        #pragma unroll
        for (int j = 0; j < 4; ++j) Ms[r][cc4 + j] = m0[j];
        {
            u16* op = tito + crow + (size_t)r * DIMC + e0 + cc4;
            bf4v w;
            #pragma unroll
            for (int j = 0; j < 4; ++j) w[j] = (short)f2bf(oa[j]);
            *(bf4v*)op = w;
        }
        __syncthreads();                 // sync 4
    }
    {
        float* mg = mout + (size_t)bh * 4096 + (size_t)r * 64 + e0 + cc4;
        *(float4*)mg = *(float4*)&Ms[r][cc4];
    }
}

// ---------------- fused attn + scanB: independent work overlapped ----------------
// Blocks [0,96): scanB (long-running, 37.5% CU coverage, latency-bound).
// Blocks [96, 96+3072): attention (MFMA-heavy). 2 blocks/CU co-reside (LDS
// union 76.8KB x2 <= 160KB) so scanB's stalls are filled by attn waves.
__global__ __launch_bounds__(256) void fused_attn_scan_kernel(
    const u16* __restrict__ qkv, u16* __restrict__ outp,
    const u16* __restrict__ tq, const float* __restrict__ tk, const float* __restrict__ tv,
    const float* __restrict__ Tm, const float* __restrict__ Sm,
    u16* __restrict__ tito, float* __restrict__ mout)
{
    __shared__ __align__(16) char smem[FUSED_SMEM];
    if (blockIdx.x < SCANB_BLOCKS)
        scanB_dev(smem, blockIdx.x, tq, tk, tv, Tm, Sm, tito, mout);
    else
        attn_dev(smem, blockIdx.x - SCANB_BLOCKS, qkv, outp);
}

// ---------------- residual + LayerNorm ----------------
__global__ __launch_bounds__(256) void ln_res_kernel(
    const void* __restrict__ xv, int xf32, const void* __restrict__ yv, int yf32,
    const float* __restrict__ g, const float* __restrict__ be,
    u16* __restrict__ outb, float* __restrict__ outf, int ldout)
{
    const int row = blockIdx.x;
    const int t = threadIdx.x;
    const size_t base = (size_t)row * DIMC;
    float vv[3];
    float s = 0.f, s2 = 0.f;
    #pragma unroll
    for (int i = 0; i < 3; ++i) {
        int d = t + i * 256;
        float a = xf32 ? ((const float*)xv)[base + d] : bf2f(((const u16*)xv)[base + d]);
        float y = yf32 ? ((const float*)yv)[base + d] : bf2f(((const u16*)yv)[base + d]);
        float w = a + y;
        vv[i] = w;
        s += w;
        s2 += w * w;
    }
    #pragma unroll
    for (int o = 32; o > 0; o >>= 1) {
        s  += __shfl_down(s, o);
        s2 += __shfl_down(s2, o);
    }
    __shared__ float rs[4], rq[4], mb[2];
    if ((t & 63) == 0) { rs[t >> 6] = s; rq[t >> 6] = s2; }
    __syncthreads();
    if (t == 0) {
        float S1 = rs[0] + rs[1] + rs[2] + rs[3];
        float S2 = rq[0] + rq[1] + rq[2] + rq[3];
        float mean = S1 * (1.f / 768.f);
        float var = S2 * (1.f / 768.f) - mean * mean;
        mb[0] = mean;
        mb[1] = rsqrtf(var + 1e-5f);
    }
    __syncthreads();
    float mean = mb[0], rstd = mb[1];
    #pragma unroll
    for (int i = 0; i < 3; ++i) {
        int d = t + i * 256;
        float v = (vv[i] - mean) * rstd * g[d] + be[d];
        if (outb) outb[(size_t)row * ldout + d] = f2bf(v);
        else      outf[(size_t)row * ldout + d] = v;
    }
}

// merged LN for x_local / x_global
__global__ __launch_bounds__(256) void ln_res2_kernel(
    const float* __restrict__ x,
    const u16* __restrict__ y0, const float* __restrict__ g0, const float* __restrict__ b0,
    u16* __restrict__ o0,
    const u16* __restrict__ y1, const float* __restrict__ g1, const float* __restrict__ b1,
    u16* __restrict__ o1, int M)
{
    int row = blockIdx.x;
    const u16* y; const float* g; const float* be; u16* ob;
    if (row < M) { y = y0; g = g0; be = b0; ob = o0; }
    else { row -= M; y = y1; g = g1; be = b1; ob = o1; }
    const int t = threadIdx.x;
    const size_t base = (size_t)row * DIMC;
    float vv[3];
    float s = 0.f, s2 = 0.f;
    #pragma unroll
    for (int i = 0; i < 3; ++i) {
        int d = t + i * 256;
        float w = x[base + d] + bf2f(y[base + d]);
        vv[i] = w;
        s += w;
        s2 += w * w;
    }
    #pragma unroll
    for (int o = 32; o > 0; o >>= 1) {
        s  += __shfl_down(s, o);
        s2 += __shfl_down(s2, o);
    }
    __shared__ float rs[4], rq[4], mb[2];
    if ((t & 63) == 0) { rs[t >> 6] = s; rq[t >> 6] = s2; }
    __syncthreads();
    if (t == 0) {
        float S1 = rs[0] + rs[1] + rs[2] + rs[3];
        float S2 = rq[0] + rq[1] + rq[2] + rq[3];
        float mean = S1 * (1.f / 768.f);
        float var = S2 * (1.f / 768.f) - mean * mean;
        mb[0] = mean;
        mb[1] = rsqrtf(var + 1e-5f);
    }
    __syncthreads();
    float mean = mb[0], rstd = mb[1];
    #pragma unroll
    for (int i = 0; i < 3; ++i) {
        int d = t + i * 256;
        float v = (vv[i] - mean) * rstd * g[d] + be[d];
        ob[(size_t)row * 1536 + d] = f2bf(v);
    }
}

// ---------------- chunked delta-rule scan: phase A ----------------
__global__ __launch_bounds__(64) void scanA_kernel(
    const u16* __restrict__ tq, const float* __restrict__ tk,
    float* __restrict__ Tm, float* __restrict__ Sm)
{
    const int bid = blockIdx.x;          // 24*32
    const int bh = bid >> 5, c = bid & 31;
    const int b = bh / NHEAD, h = bh % NHEAD;
    const int lane = threadIdx.x;

    __shared__ float Ks[64][68];
    __shared__ float As[64][68];     // A, later reused for S
    __shared__ float Ts[64][68];
    __shared__ u16   Qs[64][72];

    const size_t rowb = (size_t)b * SEQ * DIMC + h * 64;
    const int rg = lane >> 4, c4 = (lane & 15) * 4;
    #pragma unroll 4
    for (int i = 0; i < 16; ++i) {
        int row = i * 4 + rg;
        size_t g = rowb + (size_t)(c * 64 + row) * DIMC + c4;
        *(float4*)&Ks[row][c4] = *(const float4*)(tk + g);
        *(bf4v*)&Qs[row][c4]   = *(const bf4v*)(tq + g);
    }
    __syncthreads();

    float4 kr4[16];
    #pragma unroll
    for (int d4 = 0; d4 < 16; ++d4) kr4[d4] = *(float4*)&Ks[lane][d4 * 4];

    for (int t = 0; t < 64; ++t) {
        float a = 0.f;
        #pragma unroll
        for (int d4 = 0; d4 < 16; ++d4) {
            float4 kt = *(float4*)&Ks[t][d4 * 4];
            a += kt.x * kr4[d4].x + kt.y * kr4[d4].y + kt.z * kr4[d4].z + kt.w * kr4[d4].w;
        }
        As[t][lane] = (lane < t) ? LRc * a : 0.f;
    }
    Ts[0][lane] = (lane == 0) ? 1.f : 0.f;
    for (int t = 1; t < 64; ++t) {
        float s = (lane == t) ? 1.f : 0.f;
        for (int tau = 0; tau < t; ++tau)
            s -= As[t][tau] * Ts[tau][lane];
        Ts[t][lane] = s;
    }
    for (int t = 0; t < 64; ++t) {
        float a = 0.f;
        #pragma unroll
        for (int d4 = 0; d4 < 16; ++d4) {
            bf4v qt = *(bf4v*)&Qs[t][d4 * 4];
            a += bf2f((u16)qt[0]) * kr4[d4].x + bf2f((u16)qt[1]) * kr4[d4].y
               + bf2f((u16)qt[2]) * kr4[d4].z + bf2f((u16)qt[3]) * kr4[d4].w;
        }
        As[t][lane] = (lane <= t) ? a : 0.f;
    }
    __syncthreads();
    float* Tg = Tm + (size_t)bid * 4096;
    float* Sg = Sm + (size_t)bid * 4096;
    #pragma unroll 4
    for (int i = 0; i < 16; ++i) {
        int row = i * 4 + rg;
        *(float4*)(Tg + row * 64 + c4) = *(float4*)&Ts[row][c4];
        *(float4*)(Sg + row * 64 + c4) = *(float4*)&As[row][c4];
    }
}

// ---------------- gated combine ----------------
__global__ __launch_bounds__(768) void combine_kernel(
    const u16* __restrict__ xlg, const u16* __restrict__ gate, u16* __restrict__ xc)
{
    const int row = blockIdx.x;
    const int t = threadIdx.x;
    float g = bf2f(gate[(size_t)row * DIMC + t]);
    float xl = bf2f(xlg[(size_t)row * 1536 + t]);
    float xg = bf2f(xlg[(size_t)row * 1536 + 768 + t]);
    xc[(size_t)row * DIMC + t] = f2bf(g * xl + (1.f - g) * xg);
}

// ---------------- launcher ----------------
extern "C" void kernel_launch(void* const* d_in, const int* in_sizes, int n_in,
                              void* d_out, int out_size, void* d_ws, size_t ws_size,
                              hipStream_t stream) {
    const float* x          = (const float*)d_in[0];
    const float* in_proj_w  = (const float*)d_in[1];
    const float* in_proj_b  = (const float*)d_in[2];
    const float* out_proj_w = (const float*)d_in[3];
    const float* out_proj_b = (const float*)d_in[4];
    const float* ln_local_g = (const float*)d_in[5];
    const float* ln_local_b = (const float*)d_in[6];
    const float* t_wq       = (const float*)d_in[7];
    const float* t_wk       = (const float*)d_in[8];
    const float* t_wv       = (const float*)d_in[9];
    const float* t_wo       = (const float*)d_in[10];
    const float* ln_tit_g   = (const float*)d_in[11];
    const float* ln_tit_b   = (const float*)d_in[12];
    const float* gate_w     = (const float*)d_in[13];
    const float* gate_b     = (const float*)d_in[14];
    const float* cms_w1     = (const float*)d_in[15];
    const float* cms_b1     = (const float*)d_in[16];
    const float* cms_w2     = (const float*)d_in[17];
    const float* cms_b2     = (const float*)d_in[18];
    const float* ln_cms_g   = (const float*)d_in[19];
    const float* ln_cms_b   = (const float*)d_in[20];

    const int Mrows = 2 * SEQ;  // 4096

    // ---- workspace (u16 offsets), cap 37,748,736 u16 = 75,497,472 B ----
    u16* ws = (u16*)d_ws;
    u16*   qkv   = ws + 0;
    u16*   lout  = ws + 0;
    u16*   gout  = ws + 3145728;
    u16*   gact  = ws + 6291456;
    u16*   tq16  = ws + 9437184;
    u16*   wB    = ws + 9437184;      // 768x768 bf16 (589824)
    u16*   wB2   = ws + 10027008;     // second weight slot (t_wo)
    u16*   w_inp = ws + 12582912;
    float* tkf   = (float*)(ws + 12582912);
    u16*   W1S   = ws + 12582912;
    u16*   W2S   = ws + 14942208;
    float* tvf   = (float*)(ws + 18874368);
    u16*   w_tqb = ws + 25165824;
    u16*   tito  = ws + 25165824;
    u16*   w_hi  = ws + 28311552;
    u16*   w_lo  = ws + 28901376;
    u16*   w_hi2 = ws + 29491200;
    u16*   w_lo2 = ws + 30081024;
    u16*   attn_o= ws + 28311552;
    u16*   xc    = ws + 28311552;
    u16*   x_hi  = ws + 31457280;
    u16*   x_lo  = ws + 34603008;
    u16*   xlg   = ws + 31457280;
    u16*   h     = ws + 0;            // CMS h: A+B regions dead after combine

    float* out32 = (float*)d_out;
    float* cmsacc = out32;
    float* mout  = out32 + (size_t)Mrows * DIMC;

    float* Tmat = (float*)(ws + 31457280);   // G region (exact fit)
    float* Smat = out32;                     // cmsacc region as scratch pre-CMS

    auto cast = [&](const float* src, u16* dst, int n) {
        cast_f2b_kernel<<<(n + 1023) / 1024, 256, 0, stream>>>(src, dst, n);
    };
    auto gemm = [&](const u16* A, const u16* W, const float* bias, u16* ob, float* of,
                    int M, int N, int K, int act, int mode, float oscale) {
        gemm128_kernel<<<dim3(M / 128, N / 128), 256, 0, stream>>>(
            A, W, bias, ob, of, N, K, act, mode, oscale);
    };
    auto split = [&](const float* src, u16* hi, u16* lo, int n) {
        cast_split_kernel<<<(n + 1023) / 1024, 256, 0, stream>>>(src, hi, lo, n);
    };

    // 1. split-cast x
    split(x, x_hi, x_lo, Mrows * DIMC);
    // 2. qkv projection
    cast(in_proj_w, w_inp, QKVC * DIMC);
    gemm(x_hi, w_inp, in_proj_b, qkv, nullptr, Mrows, QKVC, DIMC, 0, 0, 0.f);
    // 3+4. tk & tv split-precision in ONE dual launch
    split(t_wk, w_hi, w_lo, DIMC * DIMC);
    split(t_wv, w_hi2, w_lo2, DIMC * DIMC);
    gemm_split_kernel<<<dim3(Mrows / 64, DIMC / 64, 2), 256, 0, stream>>>(
        x_hi, x_lo, w_hi, w_lo, tkf, w_hi2, w_lo2, tvf, Mrows, DIMC, DIMC);
    // 5. tq (bf16)
    cast(t_wq, w_tqb, DIMC * DIMC);
    gemm(x_hi, w_tqb, nullptr, tq16, nullptr, Mrows, DIMC, DIMC, 0, 0, 0.f);
    // 6. scanA (parallel phase; must precede scanB)
    scanA_kernel<<<24 * 32, 64, 0, stream>>>(tq16, tkf, Tmat, Smat);
    // 7. FUSED attn + scanB: independent work, overlapped in one launch.
    //    scanB blocks first (early dispatch); attn fills remaining CU slots.
    //    (tito overwrites w_tqb: tq gemm done; attn_o overwrites w_hi/lo: split done)
    fused_attn_scan_kernel<<<SCANB_BLOCKS + 128 * 24, 256, 0, stream>>>(
        qkv, attn_o, tq16, tkf, tvf, Tmat, Smat, tito, mout);
    // 8+10. out_proj + titans out_proj in ONE dual launch
    cast2_f2b_kernel<<<dim3((DIMC * DIMC + 1023) / 1024, 1, 2), 256, 0, stream>>>(
        out_proj_w, wB, t_wo, wB2, DIMC * DIMC);
    gemm128_dual_kernel<<<dim3(Mrows / 128, DIMC / 128, 2), 256, 0, stream>>>(
        attn_o, wB, out_proj_b, lout, tito, wB2, nullptr, gout, DIMC, DIMC);
    // 9+11. x_local & x_global LayerNorms in ONE launch
    ln_res2_kernel<<<2 * Mrows, 256, 0, stream>>>(
        x, lout, ln_local_g, ln_local_b, xlg,
        gout, ln_tit_g, ln_tit_b, xlg + 768, Mrows);
    // 12. gate
    cast(gate_w, wB, DIMC * 2 * DIMC);
    gemm(xlg, wB, gate_b, gact, nullptr, Mrows, DIMC, 2 * DIMC, 2, 0, 0.f);
    // 13. combine -> xc
    combine_kernel<<<Mrows, 768, 0, stream>>>(xlg, gact, xc);
    // 14. CMS merged over full M; gemm2 K-split x4 with atomicAdd into
    //     pre-zeroed cmsacc (overwrites Smat scratch: fused kernel done).
    hipMemsetAsync(cmsacc, 0, (size_t)Mrows * DIMC * sizeof(float), stream);
    for (int l = 0; l < 4; ++l) {
        cast2_f2b_kernel<<<dim3((2359296 + 1023) / 1024, 1, 2), 256, 0, stream>>>(
            cms_w1 + (size_t)l * 2359296, W1S, cms_w2 + (size_t)l * 2359296, W2S, 2359296);
        gemm(xc, W1S, cms_b1 + l * 3072, h, nullptr, Mrows, 3072, DIMC, 1, 0, 0.f);
        gemm128_ksplit_kernel<<<dim3(Mrows / 128, DIMC / 128, 4), 256, 0, stream>>>(
            h, W2S, cms_b2 + l * DIMC, cmsacc, DIMC, 3072, 768, 0.25f);
    }
    // 15. final LN -> d_out
    ln_res_kernel<<<Mrows, 256, 0, stream>>>(xc, 0, cmsacc, 1, ln_cms_g, ln_cms_b, nullptr, out32, DIMC);

    (void)in_sizes; (void)n_in; (void)out_size; (void)ws_size;
}